// Round 5
// baseline (1034.636 us; speedup 1.0000x reference)
//
#include <hip/hip_runtime.h>
#include <hip/hip_bf16.h>

typedef __hip_bfloat16 bf16;

#define Bc 2
#define Nc 512
#define Rc 64
#define Tc 128
#define Ec 64
#define Hc 8
#define THc 1024
#define FFc 256

__device__ __forceinline__ bf16  f2b(float x){ return __float2bfloat16(x); }
__device__ __forceinline__ float us2f(unsigned short u){
  union { unsigned int i; float f; } c; c.i = ((unsigned int)u) << 16; return c.f;
}
__device__ __forceinline__ float clip5(float x){ return fminf(fmaxf(x, -5.0f), 5.0f); }

__device__ __forceinline__ float wave_sum64(float v){
#pragma unroll
  for (int o = 32; o > 0; o >>= 1) v += __shfl_xor(v, o, 64);
  return v;
}
// two interleaved wave sums (ILP across the serial shuffle chain)
__device__ __forceinline__ void wave_sum64x2(float& a, float& b){
#pragma unroll
  for (int o = 32; o > 0; o >>= 1){
    a += __shfl_xor(a, o, 64);
    b += __shfl_xor(b, o, 64);
  }
}

// sum across the 16 lanes that co-own one row (lanes are 16-aligned groups)
__device__ __forceinline__ float rowred16_sum(float v){
  v += __shfl_xor(v, 1, 64);
  v += __shfl_xor(v, 2, 64);
  v += __shfl_xor(v, 4, 64);
  v += __shfl_xor(v, 8, 64);
  return v;
}

// ---------------- prep: ds = D_S@W_emb + b_emb ; qhat_sr = I_param(head)@Wq_sr ----
__global__ __launch_bounds__(64) void k_prep(
    const float* __restrict__ DS, const float* __restrict__ Wemb,
    const float* __restrict__ bemb, const float* __restrict__ Ip,
    const float* __restrict__ Wq, float* __restrict__ ds, float* __restrict__ qhat)
{
  int bid = blockIdx.x, t = threadIdx.x;
  if (bid < Nc){
    int n = bid, e = t;
    __shared__ float row[Rc];
    row[t] = DS[n*Rc + t];
    __syncthreads();
    float acc = bemb[e];
    for (int r = 0; r < Rc; ++r) acc += row[r] * Wemb[r*Ec + e];
    ds[n*Ec + e] = acc;
  } else {
    int r = bid - Nc;
    __shared__ float irow[Ec];
    irow[t] = Ip[r*Ec + t];
    __syncthreads();
    int h = t >> 3, d = t & 7;
    float acc = 0.0f;
#pragma unroll
    for (int d0 = 0; d0 < 8; ++d0) acc += irow[h*8 + d0] * Wq[d0*8 + d];
    qhat[r*Ec + h*8 + d] = acc;   // [R][H][D]
  }
}

// ---------------- khat_sr = (key+ds)@Wk per head; vhat_sr = value@Wv --------------
__global__ __launch_bounds__(256) void k_proj_sr(
    const float* __restrict__ key, const float* __restrict__ value,
    const float* __restrict__ ds, const float* __restrict__ Wk,
    const float* __restrict__ Wv, float* __restrict__ khat, float* __restrict__ vhat)
{
  __shared__ float wk[64], wv[64];
  int t = threadIdx.x;
  if (t < 64){ wk[t] = Wk[t]; wv[t] = Wv[t]; }
  __syncthreads();
  int u = blockIdx.x*256 + t;              // (b,n,t,h) unit, < 1048576
  int h = u & 7;
  int nt = u >> 3;                         // (b*N+n)*T + t
  int n = (nt / Tc) % Nc;
  const float* kp = key + (size_t)u*8;
  const float* vp = value + (size_t)u*8;
  const float* dsp = ds + n*Ec + h*8;
  float kin[8], vin[8];
#pragma unroll
  for (int d = 0; d < 8; ++d){ kin[d] = kp[d] + dsp[d]; vin[d] = vp[d]; }
  float* ko = khat + (size_t)u*8;
  float* vo = vhat + (size_t)u*8;
#pragma unroll
  for (int d = 0; d < 8; ++d){
    float ka = 0.0f, va = 0.0f;
#pragma unroll
    for (int d0 = 0; d0 < 8; ++d0){ ka += kin[d0]*wk[d0*8+d]; va += vin[d0]*wv[d0*8+d]; }
    ko[d] = ka; vo[d] = va;
  }
}

// ---------------- asr writer: lane = t -> fully coalesced fp32 asr --------------
// block = (b, n-pair), 256 thr: n = n0 + (tid>>7), t = tid&127.
// Softmax denominator over r is in-thread (no shuffles). Also emits the
// reciprocal denominators rDsr[b][n][t][h] for k_attn_sr to reuse.
__global__ __launch_bounds__(256) void k_asr_write(
    const float* __restrict__ khat, const float* __restrict__ qhat,
    const int* __restrict__ adj_sr, float* __restrict__ o_asr,
    float* __restrict__ rDsr)
{
  __shared__ float ql[4096];                 // q [r][h*8+d]
  const float EXPM5 = 0.006737946999085467f; // exp(-5)
  int bid = blockIdx.x;                      // b*256 + npair
  int b = bid >> 8, np = bid & 255;
  int tid = threadIdx.x;
  int n = np*2 + (tid >> 7);
  int t = tid & 127;
#pragma unroll
  for (int i = 0; i < 16; ++i) ql[i*256 + tid] = qhat[i*256 + tid];
  __syncthreads();
  const float* kp = khat + ((size_t)((b*Nc + n)*Tc + t))*Ec;
  float kr[64];
#pragma unroll
  for (int i = 0; i < 16; ++i) *(float4*)&kr[i*4] = *(const float4*)&kp[i*4];

  // pass 1: denominators s[h] = sum_r exp(e[r][h])
  float s[8] = {0,0,0,0,0,0,0,0};
  for (int r = 0; r < 64; ++r){
    int m = adj_sr[n*Rc + r];                // wave-uniform
    if (m){
      const float* qr = &ql[r*64];
#pragma unroll
      for (int h = 0; h < 8; ++h){
        float4 qa = *(const float4*)&qr[h*8];
        float4 qb = *(const float4*)&qr[h*8 + 4];
        float e = qa.x*kr[h*8+0] + qa.y*kr[h*8+1] + qa.z*kr[h*8+2] + qa.w*kr[h*8+3]
                + qb.x*kr[h*8+4] + qb.y*kr[h*8+5] + qb.z*kr[h*8+6] + qb.w*kr[h*8+7];
        s[h] += __expf(clip5(e*0.125f));
      }
    } else {
#pragma unroll
      for (int h = 0; h < 8; ++h) s[h] += EXPM5;
    }
  }
  float rs_[8];
#pragma unroll
  for (int h = 0; h < 8; ++h) rs_[h] = __builtin_amdgcn_rcpf(s[h]);
  {
    size_t dbase = ((size_t)((b*Nc + n)*Tc + t))*8;   // [B][N][T][H]
    *(float4*)&rDsr[dbase]     = make_float4(rs_[0], rs_[1], rs_[2], rs_[3]);
    *(float4*)&rDsr[dbase + 4] = make_float4(rs_[4], rs_[5], rs_[6], rs_[7]);
  }

  // pass 2: normalize + coalesced store
  for (int r = 0; r < 64; ++r){
    int m = adj_sr[n*Rc + r];
    float a[8];
    if (m){
      const float* qr = &ql[r*64];
#pragma unroll
      for (int h = 0; h < 8; ++h){
        float4 qa = *(const float4*)&qr[h*8];
        float4 qb = *(const float4*)&qr[h*8 + 4];
        float e = qa.x*kr[h*8+0] + qa.y*kr[h*8+1] + qa.z*kr[h*8+2] + qa.w*kr[h*8+3]
                + qb.x*kr[h*8+4] + qb.y*kr[h*8+5] + qb.z*kr[h*8+6] + qb.w*kr[h*8+7];
        a[h] = __expf(clip5(e*0.125f)) * rs_[h];
      }
    } else {
#pragma unroll
      for (int h = 0; h < 8; ++h) a[h] = EXPM5 * rs_[h];
    }
    size_t ao = ((size_t)((b*Rc + r)*Nc + n))*THc + t*8;  // [B][R][N][T*8+h]
    *(float4*)&o_asr[ao]     = make_float4(a[0], a[1], a[2], a[3]);
    *(float4*)&o_asr[ao + 4] = make_float4(a[4], a[5], a[6], a[7]);
  }
}

// ---------------- sr attention (PV only): block=(b,t,h) x 4 waves ---------------
// softmax denominators PRECOMPUTED by k_asr_write (rD, wave-uniform scalar load):
// no shuffles, no divides -> pure FMA/exp throughput.
__global__ __launch_bounds__(256) void k_attn_sr(
    const float* __restrict__ khat, const float* __restrict__ vhat,
    const float* __restrict__ qhat, const int* __restrict__ adj_sr,
    const float* __restrict__ rD, float* __restrict__ pre)
{
  __shared__ float accs[4][64][8];
  int bid = blockIdx.x;
  int b = bid >> 10, th = bid & 1023;
  int t = th >> 3, h = th & 7;
  int tid = threadIdx.x;
  int r = tid & 63, w = tid >> 6;
  float q[8];
#pragma unroll
  for (int d = 0; d < 8; ++d) q[d] = qhat[r*Ec + h*8 + d];
  float acc[8] = {0,0,0,0,0,0,0,0};
  int n0 = w*128;
  for (int n = n0; n < n0 + 128; n += 2){
    size_t goA = ((size_t)((b*Nc + n)*Tc + t))*Ec + h*8;
    size_t goB = goA + (size_t)Tc*Ec;
    const float* kA = khat + goA;
    const float* kB = khat + goB;
    float eA = 0.0f, eB = 0.0f;
#pragma unroll
    for (int d = 0; d < 8; ++d){ eA += q[d]*kA[d]; eB += q[d]*kB[d]; }
    int mA = adj_sr[n*Rc + r], mB = adj_sr[(n+1)*Rc + r];
    eA = mA ? clip5(eA*0.125f) : -5.0f;
    eB = mB ? clip5(eB*0.125f) : -5.0f;
    float rdA = rD[((size_t)((b*Nc + n  )*Tc + t))*8 + h];   // wave-uniform
    float rdB = rD[((size_t)((b*Nc + n+1)*Tc + t))*8 + h];
    float aA = __expf(eA) * rdA;
    float aB = __expf(eB) * rdB;
    const float* vA = vhat + goA;
    const float* vB = vhat + goB;
#pragma unroll
    for (int d = 0; d < 8; ++d) acc[d] += aA*vA[d] + aB*vB[d];
  }
#pragma unroll
  for (int d = 0; d < 8; ++d) accs[w][r][d] = acc[d];
  __syncthreads();
  if (w == 0){
    size_t po = ((size_t)((b*Rc + r)*Tc + t))*Ec + h*8;   // [B][R][T][E]
#pragma unroll
    for (int d = 0; d < 8; ++d)
      pre[po + d] = accs[0][r][d] + accs[1][r][d] + accs[2][r][d] + accs[3][r][d];
  }
}

// ---------------- rr attention: block=(b,t,h) x 4 waves; wave=k-chunk -----------
__global__ __launch_bounds__(256) void k_attn_rr(
    const float* __restrict__ qh, const float* __restrict__ kh,
    const float* __restrict__ vh, const int* __restrict__ adj_r,
    bf16* __restrict__ att_c, float* __restrict__ pre)
{
  __shared__ float accs[4][64][8];
  int bid = blockIdx.x;
  int b = bid >> 10, th = bid & 1023;
  int t = th >> 3, h = th & 7;
  int tid = threadIdx.x;
  int q = tid & 63, w = tid >> 6;
  size_t qo = ((size_t)((b*Rc + q)*Tc + t))*Ec + h*8;
  float qv[8];
#pragma unroll
  for (int d = 0; d < 8; ++d) qv[d] = qh[qo + d];
  float acc[8] = {0,0,0,0,0,0,0,0};
  int k0 = w*16;
  for (int k = k0; k < k0 + 16; k += 2){
    size_t koA = ((size_t)((b*Rc + k)*Tc + t))*Ec + h*8;
    size_t koB = koA + (size_t)Tc*Ec;
    const float* kA = kh + koA;
    const float* kB = kh + koB;
    float eA = 0.0f, eB = 0.0f;
#pragma unroll
    for (int d = 0; d < 8; ++d){ eA += qv[d]*kA[d]; eB += qv[d]*kB[d]; }
    int mA = adj_r[q*Rc + k], mB = adj_r[q*Rc + k + 1];
    eA = mA ? clip5(eA*0.125f) : -5.0f;
    eB = mB ? clip5(eB*0.125f) : -5.0f;
    float pA = __expf(eA), pB = __expf(eB);
    float sA = pA, sB = pB;
    wave_sum64x2(sA, sB);
    float aA = pA/sA, aB = pB/sB;
    size_t ao = ((size_t)(b*Rc + k)*THc + th)*Rc + q;
    att_c[ao] = f2b(aA);                              // [B][K][TH][Q=64]
    att_c[ao + (size_t)THc*Rc] = f2b(aB);
    const float* vA = vh + koA;
    const float* vB = vh + koB;
#pragma unroll
    for (int d = 0; d < 8; ++d) acc[d] += aA*vA[d] + aB*vB[d];
  }
#pragma unroll
  for (int d = 0; d < 8; ++d) accs[w][q][d] = acc[d];
  __syncthreads();
  if (w == 0){
#pragma unroll
    for (int d = 0; d < 8; ++d)
      pre[qo + d] = accs[0][q][d] + accs[1][q][d] + accs[2][q][d] + accs[3][q][d];
  }
}

// ------- rs attention (PV + denominators): block=(b,t,h) x 512 thr, thread=q ----
// No att-tensor write: emits reciprocal denominators rDrs[b][k][t][h] instead.
__global__ __launch_bounds__(512) void k_attn_rs(
    const float* __restrict__ query, const float* __restrict__ ds,
    const float* __restrict__ Wq, const float* __restrict__ kh,
    const float* __restrict__ vh, float* __restrict__ rDrs,
    float* __restrict__ pre)
{
  __shared__ float wq[64];
  __shared__ float kl[64][8];
  __shared__ float vl[64][8];
  __shared__ float redS[2][2][8];
  int bid = blockIdx.x;
  int b = bid >> 10, th = bid & 1023;
  int t = th >> 3, h = th & 7;
  int q = threadIdx.x;
  if (q < 64) wq[q] = Wq[q];
  {
    int kk = q >> 3, d = q & 7;
    size_t o = ((size_t)((b*Rc + kk)*Tc + t))*Ec + h*8 + d;
    kl[kk][d] = kh[o];
    vl[kk][d] = vh[o];
  }
  __syncthreads();
  size_t qro = ((size_t)((b*Nc + q)*Tc + t))*Ec + h*8;
  const float* dsp = ds + q*Ec + h*8;
  float xin[8], qv[8];
#pragma unroll
  for (int d = 0; d < 8; ++d) xin[d] = query[qro + d] + dsp[d];
#pragma unroll
  for (int d = 0; d < 8; ++d){
    float a = 0.0f;
#pragma unroll
    for (int d0 = 0; d0 < 8; ++d0) a += xin[d0]*wq[d0*8 + d];
    qv[d] = a;
  }
  float acc[8] = {0,0,0,0,0,0,0,0};
  int lane = q & 63, wv = q >> 6;
  for (int k = 0; k < 64; k += 2){
    float eA = 0.0f, eB = 0.0f;
#pragma unroll
    for (int d = 0; d < 8; ++d){ eA += qv[d]*kl[k][d]; eB += qv[d]*kl[k+1][d]; }
    eA = clip5(eA*0.125f);
    eB = clip5(eB*0.125f);
    float pA = __expf(eA), pB = __expf(eB);
    float sA = pA, sB = pB;
    wave_sum64x2(sA, sB);
    int pb = (k >> 1) & 1;
    if (lane == 0){ redS[pb][0][wv] = sA; redS[pb][1][wv] = sB; }
    __syncthreads();
    float stA = 0.0f, stB = 0.0f;
#pragma unroll
    for (int i = 0; i < 8; ++i){ stA += redS[pb][0][i]; stB += redS[pb][1][i]; }
    if (q == 0){
      rDrs[((size_t)((b*Rc + k  )*Tc + t))*8 + h] = __builtin_amdgcn_rcpf(stA);
      rDrs[((size_t)((b*Rc + k+1)*Tc + t))*8 + h] = __builtin_amdgcn_rcpf(stB);
    }
    float aA = pA/stA, aB = pB/stB;
#pragma unroll
    for (int d = 0; d < 8; ++d) acc[d] += aA*vl[k][d] + aB*vl[k+1][d];
  }
#pragma unroll
  for (int d = 0; d < 8; ++d) pre[qro + d] = acc[d];         // [B][N][T][E]
}

// ---------------- ars writer: lane = t -> fully coalesced fp32 ars --------------
// block = (b, q4): 512 thr = 128 t x 4 q. Recomputes qv (matches k_attn_rs) and
// e per (q,k), multiplies by precomputed rDrs, stores [q][k][t*8+h] (2KB bursts).
// kh for rs is 4MB total -> L2-resident.
__global__ __launch_bounds__(512) void k_ars_write(
    const float* __restrict__ query, const float* __restrict__ ds,
    const float* __restrict__ Wq, const float* __restrict__ kh,
    const float* __restrict__ rD, float* __restrict__ o_ars)
{
  __shared__ float wq[64];
  int bid = blockIdx.x;                      // b*128 + qc
  int b = bid >> 7, qc = bid & 127;
  int tid = threadIdx.x;
  int t = tid & 127, ql = tid >> 7;
  int q = qc*4 + ql;
  if (tid < 64) wq[tid] = Wq[tid];
  __syncthreads();
  size_t qro = ((size_t)((b*Nc + q)*Tc + t))*Ec;
  float xin[64];
#pragma unroll
  for (int i = 0; i < 16; ++i){
    float4 v = *(const float4*)&query[qro + i*4];
    float4 dv = *(const float4*)&ds[q*Ec + i*4];
    xin[i*4+0] = v.x + dv.x;
    xin[i*4+1] = v.y + dv.y;
    xin[i*4+2] = v.z + dv.z;
    xin[i*4+3] = v.w + dv.w;
  }
  float qv[64];
#pragma unroll
  for (int h = 0; h < 8; ++h){
#pragma unroll
    for (int d = 0; d < 8; ++d){
      float a = 0.0f;
#pragma unroll
      for (int d0 = 0; d0 < 8; ++d0) a += xin[h*8 + d0]*wq[d0*8 + d];
      qv[h*8 + d] = a;
    }
  }
  for (int k = 0; k < 64; ++k){
    size_t kro = ((size_t)((b*Rc + k)*Tc + t))*Ec;
    const float* kp = kh + kro;
    float4 rd0 = *(const float4*)&rD[((size_t)((b*Rc + k)*Tc + t))*8];
    float4 rd1 = *(const float4*)&rD[((size_t)((b*Rc + k)*Tc + t))*8 + 4];
    float a[8];
#pragma unroll
    for (int h = 0; h < 8; ++h){
      float e = 0.0f;
#pragma unroll
      for (int d = 0; d < 8; ++d) e += qv[h*8 + d]*kp[h*8 + d];
      a[h] = __expf(clip5(e*0.125f));
    }
    a[0] *= rd0.x; a[1] *= rd0.y; a[2] *= rd0.z; a[3] *= rd0.w;
    a[4] *= rd1.x; a[5] *= rd1.y; a[6] *= rd1.z; a[7] *= rd1.w;
    size_t ao = ((size_t)((b*Nc + q)*Rc + k))*THc + t*8;  // [B][Q][K][T*8+h]
    *(float4*)&o_ars[ao]     = make_float4(a[0], a[1], a[2], a[3]);
    *(float4*)&o_ars[ao + 4] = make_float4(a[4], a[5], a[6], a[7]);
  }
}

// ---- transpose+widen: src bf16 [B][W][TH][C] -> dst fp32 [((b*C+c)*W+w)*TH+th] --
__global__ __launch_bounds__(256) void k_transpose(
    const unsigned short* __restrict__ src, float* __restrict__ dst,
    int W, int C)
{
  __shared__ unsigned short tile[64][66];
  int bid = blockIdx.x;
  int nct = C >> 6;
  int ct = bid % nct; bid /= nct;
  int tht = bid & 15; bid >>= 4;
  int w = bid % W; int b = bid / W;
  int tt = threadIdx.x;
  {
    int cs = tt & 63, i0 = tt >> 6;
    const unsigned short* sb = src + ((size_t)(b*W + w)*THc + tht*64)*C + ct*64;
#pragma unroll
    for (int p = 0; p < 16; ++p){
      int i = i0 + p*4;
      tile[i][cs] = sb[(size_t)i*C + cs];
    }
  }
  __syncthreads();
  {
    int i = tt & 63, c0 = tt >> 6;
#pragma unroll
    for (int p = 0; p < 16; ++p){
      int cs = c0 + p*4;
      int c = ct*64 + cs;
      dst[((size_t)(b*C + c)*W + w)*THc + tht*64 + i] = us2f(tile[i][cs]);
    }
  }
}

// -------- Wo projection: wave per row, (sum of nparts partials) @ Wo + bo -------
__global__ __launch_bounds__(256) void k_wo(
    const float* __restrict__ pre, int nparts, int pstride,
    const float* __restrict__ Wo,
    const float* __restrict__ bo, float* __restrict__ outf,
    float* __restrict__ outf2, int nrows)
{
  int gt = blockIdx.x*256 + threadIdx.x;
  int row = gt >> 6, lane = gt & 63;
  if (row >= nrows) return;
  float xin = 0.0f;
  for (int p2 = 0; p2 < nparts; ++p2)
    xin += pre[(size_t)p2*pstride + (size_t)row*64 + lane];
  float acc = bo[lane];
  for (int e = 0; e < 64; ++e){
    float xe = __shfl(xin, e, 64);
    acc += xe * Wo[e*64 + lane];
  }
  outf[(size_t)row*64 + lane] = acc;
  if (outf2) outf2[(size_t)row*64 + lane] = acc;
}

// ---------------- per-head triple projection from [rows][64] fp32 ---------------
__global__ __launch_bounds__(256) void k_proj3(
    const float* __restrict__ src, const float* Wq, const float* Wk, const float* Wv,
    float* qh, float* kh, float* vh, int nunits)
{
  __shared__ float wq[64], wk[64], wv[64];
  int t = threadIdx.x;
  if (t < 64){
    wq[t] = Wq ? Wq[t] : 0.0f;
    wk[t] = Wk[t];
    wv[t] = Wv[t];
  }
  __syncthreads();
  int u = blockIdx.x*256 + t;
  if (u >= nunits) return;
  const float* sp = src + (size_t)u*8;
  float xin[8];
#pragma unroll
  for (int d = 0; d < 8; ++d) xin[d] = sp[d];
#pragma unroll
  for (int d = 0; d < 8; ++d){
    float qa = 0.0f, ka = 0.0f, va = 0.0f;
#pragma unroll
    for (int d0 = 0; d0 < 8; ++d0){
      qa += xin[d0]*wq[d0*8 + d];
      ka += xin[d0]*wk[d0*8 + d];
      va += xin[d0]*wv[d0*8 + d];
    }
    if (qh) qh[(size_t)u*8 + d] = qa;
    kh[(size_t)u*8 + d] = ka;
    vh[(size_t)u*8 + d] = va;
  }
}

// =====================================================================
// fused tail: LDS-tiled register-blocked fp32 GEMMs.
// block = 256 thr = 64 rows; thread = 4 rows x 4 cols micro-tile.
// =====================================================================
__device__ __forceinline__ void gemm64x64(
    const float (* __restrict__ Xs)[68], const float* __restrict__ W,
    int Wld, int r0, int c0, float acc[4][4])
{
#pragma unroll 4
  for (int k = 0; k < 64; k += 4){
    float4 xr0 = *(const float4*)&Xs[r0+0][k];
    float4 xr1 = *(const float4*)&Xs[r0+1][k];
    float4 xr2 = *(const float4*)&Xs[r0+2][k];
    float4 xr3 = *(const float4*)&Xs[r0+3][k];
#pragma unroll
    for (int kk = 0; kk < 4; ++kk){
      float4 w = *(const float4*)&W[(size_t)(k+kk)*Wld + c0];
      float x0 = (&xr0.x)[kk], x1 = (&xr1.x)[kk];
      float x2 = (&xr2.x)[kk], x3 = (&xr3.x)[kk];
      acc[0][0] += x0*w.x; acc[0][1] += x0*w.y; acc[0][2] += x0*w.z; acc[0][3] += x0*w.w;
      acc[1][0] += x1*w.x; acc[1][1] += x1*w.y; acc[1][2] += x1*w.z; acc[1][3] += x1*w.w;
      acc[2][0] += x2*w.x; acc[2][1] += x2*w.y; acc[2][2] += x2*w.z; acc[2][3] += x2*w.w;
      acc[3][0] += x3*w.x; acc[3][1] += x3*w.y; acc[3][2] += x3*w.z; acc[3][3] += x3*w.w;
    }
  }
}

// per-row LN on the 4x4 tile (row spread across 16 lanes)
__device__ __forceinline__ void ln64(
    const float acc[4][4], float4 g, float4 b, float out[4][4])
{
#pragma unroll
  for (int i = 0; i < 4; ++i){
    float s = acc[i][0] + acc[i][1] + acc[i][2] + acc[i][3];
    float m = rowred16_sum(s) * (1.0f/64.0f);
    float d0 = acc[i][0] - m, d1 = acc[i][1] - m, d2 = acc[i][2] - m, d3 = acc[i][3] - m;
    float vv = d0*d0 + d1*d1 + d2*d2 + d3*d3;
    float var = rowred16_sum(vv) * (1.0f/64.0f);
    float rs = rsqrtf(var + 1e-5f);
    out[i][0] = d0*rs*g.x + b.x;
    out[i][1] = d1*rs*g.y + b.y;
    out[i][2] = d2*rs*g.z + b.z;
    out[i][3] = d3*rs*g.w + b.w;
  }
}

__global__ __launch_bounds__(256) void k_tail(
    const float* __restrict__ pre3, const float* __restrict__ query,
    const float* __restrict__ ds,
    const float* __restrict__ Wo, const float* __restrict__ bo,
    const float* __restrict__ g1, const float* __restrict__ be1,
    const float* __restrict__ W1, const float* __restrict__ b1,
    const float* __restrict__ W2, const float* __restrict__ b2,
    const float* __restrict__ g2, const float* __restrict__ be2,
    const float* __restrict__ Wfs, const float* __restrict__ bfs,
    float* __restrict__ outp)
{
  __shared__ float Xs[64][68];
  __shared__ float Hs[64][68];
  int tid = threadIdx.x;
  int cg = tid & 15, rg = tid >> 4;
  int r0 = rg*4, c0 = cg*4;
  int row_base = blockIdx.x * 64;            // 64 rows/block; T=128 -> n const/block
  int n = (row_base >> 7) & (Nc - 1);

  // stage pre3 tile into LDS
#pragma unroll
  for (int i = 0; i < 4; ++i){
    float4 t = *(const float4*)&pre3[(size_t)(row_base + r0 + i)*64 + c0];
    *(float4*)&Xs[r0+i][c0] = t;
  }

  float4 bo4  = *(const float4*)&bo[c0];
  float4 ds4  = *(const float4*)&ds[n*64 + c0];
  float4 g14  = *(const float4*)&g1[c0];
  float4 be14 = *(const float4*)&be1[c0];
  float4 b24  = *(const float4*)&b2[c0];
  float4 g24  = *(const float4*)&g2[c0];
  float4 be24 = *(const float4*)&be2[c0];
  float4 bfs4 = *(const float4*)&bfs[c0];
  __syncthreads();

  // ---- attn = pre3 @ Wo + bo ; v0 = attn + (query + ds) ; x = LN1(v0) ----
  float acc[4][4];
#pragma unroll
  for (int i = 0; i < 4; ++i){
    acc[i][0] = bo4.x; acc[i][1] = bo4.y; acc[i][2] = bo4.z; acc[i][3] = bo4.w;
  }
  gemm64x64(Xs, Wo, 64, r0, c0, acc);
#pragma unroll
  for (int i = 0; i < 4; ++i){
    float4 qv = *(const float4*)&query[(size_t)(row_base + r0 + i)*64 + c0];
    acc[i][0] += qv.x + ds4.x;
    acc[i][1] += qv.y + ds4.y;
    acc[i][2] += qv.z + ds4.z;
    acc[i][3] += qv.w + ds4.w;
  }
  float xt[4][4];
  ln64(acc, g14, be14, xt);
  __syncthreads();                 // all Wo-GEMM reads of Xs complete
#pragma unroll
  for (int i = 0; i < 4; ++i)
    *(float4*)&Xs[r0+i][c0] = make_float4(xt[i][0], xt[i][1], xt[i][2], xt[i][3]);
  __syncthreads();                 // Xs now holds x

  // ---- ff = relu(x @ W1 + b1) @ W2 + b2, in 4 panels of 64 hidden cols ----
  float ff[4][4];
#pragma unroll
  for (int i = 0; i < 4; ++i){
    ff[i][0] = b24.x; ff[i][1] = b24.y; ff[i][2] = b24.z; ff[i][3] = b24.w;
  }
  for (int p = 0; p < 4; ++p){
    float4 b14 = *(const float4*)&b1[p*64 + c0];
    float h[4][4];
#pragma unroll
    for (int i = 0; i < 4; ++i){
      h[i][0] = b14.x; h[i][1] = b14.y; h[i][2] = b14.z; h[i][3] = b14.w;
    }
    gemm64x64(Xs, W1 + p*64, 256, r0, c0, h);
#pragma unroll
    for (int i = 0; i < 4; ++i){
      h[i][0] = fmaxf(h[i][0], 0.0f); h[i][1] = fmaxf(h[i][1], 0.0f);
      h[i][2] = fmaxf(h[i][2], 0.0f); h[i][3] = fmaxf(h[i][3], 0.0f);
    }
    __syncthreads();               // prev panel's FF2 reads of Hs complete
#pragma unroll
    for (int i = 0; i < 4; ++i)
      *(float4*)&Hs[r0+i][c0] = make_float4(h[i][0], h[i][1], h[i][2], h[i][3]);
    __syncthreads();               // Hs holds hidden panel
    gemm64x64(Hs, W2 + (size_t)p*64*64, 64, r0, c0, ff);
  }

  // ---- u0 = ff + x ; U = LN2(u0) ----
#pragma unroll
  for (int i = 0; i < 4; ++i){
    float4 xv = *(const float4*)&Xs[r0+i][c0];
    ff[i][0] += xv.x; ff[i][1] += xv.y; ff[i][2] += xv.z; ff[i][3] += xv.w;
  }
  float U[4][4];
  ln64(ff, g24, be24, U);
  __syncthreads();                 // last FF2 reads of Hs complete
#pragma unroll
  for (int i = 0; i < 4; ++i)
    *(float4*)&Hs[r0+i][c0] = make_float4(U[i][0], U[i][1], U[i][2], U[i][3]);
  __syncthreads();                 // Hs holds U

  // ---- out = U @ Wfs + bfs ----
  float o[4][4];
#pragma unroll
  for (int i = 0; i < 4; ++i){
    o[i][0] = bfs4.x; o[i][1] = bfs4.y; o[i][2] = bfs4.z; o[i][3] = bfs4.w;
  }
  gemm64x64(Hs, Wfs, 64, r0, c0, o);
#pragma unroll
  for (int i = 0; i < 4; ++i)
    *(float4*)&outp[(size_t)(row_base + r0 + i)*64 + c0] =
        make_float4(o[i][0], o[i][1], o[i][2], o[i][3]);
}

extern "C" void kernel_launch(void* const* d_in, const int* in_sizes, int n_in,
                              void* d_out, int out_size, void* d_ws, size_t ws_size,
                              hipStream_t stream)
{
  const float* value = (const float*)d_in[0];
  const float* key   = (const float*)d_in[1];
  const float* query = (const float*)d_in[2];
  const int*  adj_sr = (const int*)d_in[3];
  const int*  adj_r  = (const int*)d_in[4];
  const float* D_S   = (const float*)d_in[5];
  const float* W_emb = (const float*)d_in[6];
  const float* b_emb = (const float*)d_in[7];
  const float* I_par = (const float*)d_in[8];
  const float* g1    = (const float*)d_in[9];
  const float* be1   = (const float*)d_in[10];
  const float* g2    = (const float*)d_in[11];
  const float* be2   = (const float*)d_in[12];
  const float* W_ff1 = (const float*)d_in[13];
  const float* b_ff1 = (const float*)d_in[14];
  const float* W_ff2 = (const float*)d_in[15];
  const float* b_ff2 = (const float*)d_in[16];
  const float* W_fs  = (const float*)d_in[17];
  const float* b_fs  = (const float*)d_in[18];
  const float* Wv_sr = (const float*)d_in[19];
  const float* Wk_sr = (const float*)d_in[20];
  const float* Wq_sr = (const float*)d_in[21];
  const float* Wo_sr = (const float*)d_in[22];
  const float* bo_sr = (const float*)d_in[23];
  const float* Wv_rr = (const float*)d_in[24];
  const float* Wk_rr = (const float*)d_in[25];
  const float* Wq_rr = (const float*)d_in[26];
  const float* Wo_rr = (const float*)d_in[27];
  const float* bo_rr = (const float*)d_in[28];
  const float* Wv_rs = (const float*)d_in[29];
  const float* Wk_rs = (const float*)d_in[30];
  const float* Wq_rs = (const float*)d_in[31];
  const float* Wo_rs = (const float*)d_in[32];
  const float* bo_rs = (const float*)d_in[33];

  float* outp  = (float*)d_out;
  float* o_out = outp;
  float* o_asr = outp + 8388608;
  float* o_arr = outp + 75497472;
  float* o_ars = outp + 83886080;
  float* o_hh  = outp + 150994944;

  // ---- workspace overlay (lifetime-checked) ----
  float* wsf = (float*)d_ws;
  float* ws_ds   = wsf;                      // 32768 floats, persistent
  float* ws_qsr  = wsf + 32768;              // 4096
  float* ws_rDsr = wsf + 36864;              // 1,048,576  [B][N][T][H]
  bf16*  ws_att  = (bf16*)(wsf + 36864 + 1048576);  // rr bf16 att: 8,388,608 bf16
  float* ws_rDrs = wsf + 36864 + 1048576 + 4194304; // 131,072  [B][K][T][H]
  float* pool    = wsf + 36864 + 33554432;   // stage-local scratch pool
  // stage 1
  float* ws_ksr  = pool;                     // 8,388,608
  float* ws_vsr  = pool + 8388608;           // 8,388,608
  float* ws_pre1 = pool + 16777216;          // 1,048,576
  float* ws_hh1  = pool + 17825792;          // 1,048,576
  // stage 2 (ksr/vsr dead by now)
  float* ws_qrr  = pool;                     // 1,048,576
  float* ws_krr  = pool + 1048576;
  float* ws_vrr  = pool + 2097152;
  float* ws_pre2 = pool + 3145728;
  float* ws_hh2  = pool + 4194304;
  // stage 3
  float* ws_krs  = pool + 5242880;
  float* ws_vrs  = pool + 6291456;
  float* ws_pre3 = pool + 7340032;           // 8,388,608

  // ---- stage 1: sr attention (denominator+asr writer first, then PV) ----
  k_prep<<<576, 64, 0, stream>>>(D_S, W_emb, b_emb, I_par, Wq_sr, ws_ds, ws_qsr);
  k_proj_sr<<<4096, 256, 0, stream>>>(key, value, ws_ds, Wk_sr, Wv_sr, ws_ksr, ws_vsr);
  k_asr_write<<<512, 256, 0, stream>>>(ws_ksr, ws_qsr, adj_sr, o_asr, ws_rDsr);
  k_attn_sr<<<2048, 256, 0, stream>>>(ws_ksr, ws_vsr, ws_qsr, adj_sr,
                                      ws_rDsr, ws_pre1);
  k_wo<<<4096, 256, 0, stream>>>(ws_pre1, 1, 0, Wo_sr, bo_sr,
                                 ws_hh1, (float*)nullptr, 16384);

  // ---- stage 2: rr attention ----
  k_proj3<<<512, 256, 0, stream>>>(ws_hh1, Wq_rr, Wk_rr, Wv_rr,
                                   ws_qrr, ws_krr, ws_vrr, 131072);
  k_attn_rr<<<2048, 256, 0, stream>>>(ws_qrr, ws_krr, ws_vrr, adj_r, ws_att, ws_pre2);
  k_transpose<<<2048, 256, 0, stream>>>((const unsigned short*)ws_att, o_arr, 64, 64);
  k_wo<<<4096, 256, 0, stream>>>(ws_pre2, 1, 0, Wo_rr, bo_rr, ws_hh2, o_hh, 16384);

  // ---- stage 3: rs attention (PV+denominators, then coalesced ars writer) ----
  k_proj3<<<512, 256, 0, stream>>>(ws_hh2, (const float*)nullptr, Wk_rs, Wv_rs,
                                   (float*)nullptr, ws_krs, ws_vrs, 131072);
  k_attn_rs<<<2048, 512, 0, stream>>>(query, ws_ds, Wq_rs, ws_krs, ws_vrs,
                                      ws_rDrs, ws_pre3);
  k_ars_write<<<256, 512, 0, stream>>>(query, ws_ds, Wq_rs, ws_krs,
                                       ws_rDrs, o_ars);

  // ---- tail: Wo_rs + LN + FF + LN + W_fs (fused, LDS-tiled fp32 GEMM) ----
  k_tail<<<2048, 256, 0, stream>>>(ws_pre3, query, ws_ds, Wo_rs, bo_rs,
                                   g1, be1, W_ff1, b_ff1, W_ff2, b_ff2,
                                   g2, be2, W_fs, b_fs, o_out);
}

// Round 6
// 855.155 us; speedup vs baseline: 1.2099x; 1.2099x over previous
//
#include <hip/hip_runtime.h>
#include <hip/hip_bf16.h>

typedef __hip_bfloat16 bf16;

#define Bc 2
#define Nc 512
#define Rc 64
#define Tc 128
#define Ec 64
#define Hc 8
#define THc 1024
#define FFc 256

__device__ __forceinline__ bf16  f2b(float x){ return __float2bfloat16(x); }
__device__ __forceinline__ float us2f(unsigned short u){
  union { unsigned int i; float f; } c; c.i = ((unsigned int)u) << 16; return c.f;
}
__device__ __forceinline__ float clip5(float x){ return fminf(fmaxf(x, -5.0f), 5.0f); }

__device__ __forceinline__ float wave_sum64(float v){
#pragma unroll
  for (int o = 32; o > 0; o >>= 1) v += __shfl_xor(v, o, 64);
  return v;
}
// two interleaved wave sums (ILP across the serial shuffle chain)
__device__ __forceinline__ void wave_sum64x2(float& a, float& b){
#pragma unroll
  for (int o = 32; o > 0; o >>= 1){
    a += __shfl_xor(a, o, 64);
    b += __shfl_xor(b, o, 64);
  }
}
// four interleaved wave sums
__device__ __forceinline__ void wave_sum64x4(float& a, float& b, float& c, float& d){
#pragma unroll
  for (int o = 32; o > 0; o >>= 1){
    a += __shfl_xor(a, o, 64);
    b += __shfl_xor(b, o, 64);
    c += __shfl_xor(c, o, 64);
    d += __shfl_xor(d, o, 64);
  }
}

// sum across the 16 lanes that co-own one row (lanes are 16-aligned groups)
__device__ __forceinline__ float rowred16_sum(float v){
  v += __shfl_xor(v, 1, 64);
  v += __shfl_xor(v, 2, 64);
  v += __shfl_xor(v, 4, 64);
  v += __shfl_xor(v, 8, 64);
  return v;
}

// ---------------- prep: ds = D_S@W_emb + b_emb ; qhat_sr = I_param(head)@Wq_sr ----
__global__ __launch_bounds__(64) void k_prep(
    const float* __restrict__ DS, const float* __restrict__ Wemb,
    const float* __restrict__ bemb, const float* __restrict__ Ip,
    const float* __restrict__ Wq, float* __restrict__ ds, float* __restrict__ qhat)
{
  int bid = blockIdx.x, t = threadIdx.x;
  if (bid < Nc){
    int n = bid, e = t;
    __shared__ float row[Rc];
    row[t] = DS[n*Rc + t];
    __syncthreads();
    float acc = bemb[e];
    for (int r = 0; r < Rc; ++r) acc += row[r] * Wemb[r*Ec + e];
    ds[n*Ec + e] = acc;
  } else {
    int r = bid - Nc;
    __shared__ float irow[Ec];
    irow[t] = Ip[r*Ec + t];
    __syncthreads();
    int h = t >> 3, d = t & 7;
    float acc = 0.0f;
#pragma unroll
    for (int d0 = 0; d0 < 8; ++d0) acc += irow[h*8 + d0] * Wq[d0*8 + d];
    qhat[r*Ec + h*8 + d] = acc;   // [R][H][D]
  }
}

// ---------------- khat_sr = (key+ds)@Wk per head; vhat_sr = value@Wv --------------
__global__ __launch_bounds__(256) void k_proj_sr(
    const float* __restrict__ key, const float* __restrict__ value,
    const float* __restrict__ ds, const float* __restrict__ Wk,
    const float* __restrict__ Wv, float* __restrict__ khat, float* __restrict__ vhat)
{
  __shared__ float wk[64], wv[64];
  int t = threadIdx.x;
  if (t < 64){ wk[t] = Wk[t]; wv[t] = Wv[t]; }
  __syncthreads();
  int u = blockIdx.x*256 + t;              // (b,n,t,h) unit, < 1048576
  int h = u & 7;
  int nt = u >> 3;                         // (b*N+n)*T + t
  int n = (nt / Tc) % Nc;
  const float* kp = key + (size_t)u*8;
  const float* vp = value + (size_t)u*8;
  const float* dsp = ds + n*Ec + h*8;
  float kin[8], vin[8];
#pragma unroll
  for (int d = 0; d < 8; ++d){ kin[d] = kp[d] + dsp[d]; vin[d] = vp[d]; }
  float* ko = khat + (size_t)u*8;
  float* vo = vhat + (size_t)u*8;
#pragma unroll
  for (int d = 0; d < 8; ++d){
    float ka = 0.0f, va = 0.0f;
#pragma unroll
    for (int d0 = 0; d0 < 8; ++d0){ ka += kin[d0]*wk[d0*8+d]; va += vin[d0]*wv[d0*8+d]; }
    ko[d] = ka; vo[d] = va;
  }
}

// ---------------- asr writer: lane = t -> fully coalesced fp32 asr --------------
// block = (b, n-pair), 256 thr: n = n0 + (tid>>7), t = tid&127.
// Softmax denominator over r is in-thread (no shuffles). Also emits the
// reciprocal denominators rDsr[b][n][t][h] for k_attn_sr to reuse.
__global__ __launch_bounds__(256) void k_asr_write(
    const float* __restrict__ khat, const float* __restrict__ qhat,
    const int* __restrict__ adj_sr, float* __restrict__ o_asr,
    float* __restrict__ rDsr)
{
  __shared__ float ql[4096];                 // q [r][h*8+d]
  const float EXPM5 = 0.006737946999085467f; // exp(-5)
  int bid = blockIdx.x;                      // b*256 + npair
  int b = bid >> 8, np = bid & 255;
  int tid = threadIdx.x;
  int n = np*2 + (tid >> 7);
  int t = tid & 127;
#pragma unroll
  for (int i = 0; i < 16; ++i) ql[i*256 + tid] = qhat[i*256 + tid];
  __syncthreads();
  const float* kp = khat + ((size_t)((b*Nc + n)*Tc + t))*Ec;
  float kr[64];
#pragma unroll
  for (int i = 0; i < 16; ++i) *(float4*)&kr[i*4] = *(const float4*)&kp[i*4];

  // pass 1: denominators s[h] = sum_r exp(e[r][h])
  float s[8] = {0,0,0,0,0,0,0,0};
  for (int r = 0; r < 64; ++r){
    int m = adj_sr[n*Rc + r];                // wave-uniform
    if (m){
      const float* qr = &ql[r*64];
#pragma unroll
      for (int h = 0; h < 8; ++h){
        float4 qa = *(const float4*)&qr[h*8];
        float4 qb = *(const float4*)&qr[h*8 + 4];
        float e = qa.x*kr[h*8+0] + qa.y*kr[h*8+1] + qa.z*kr[h*8+2] + qa.w*kr[h*8+3]
                + qb.x*kr[h*8+4] + qb.y*kr[h*8+5] + qb.z*kr[h*8+6] + qb.w*kr[h*8+7];
        s[h] += __expf(clip5(e*0.125f));
      }
    } else {
#pragma unroll
      for (int h = 0; h < 8; ++h) s[h] += EXPM5;
    }
  }
  float rs_[8];
#pragma unroll
  for (int h = 0; h < 8; ++h) rs_[h] = __builtin_amdgcn_rcpf(s[h]);
  {
    size_t dbase = ((size_t)((b*Nc + n)*Tc + t))*8;   // [B][N][T][H]
    *(float4*)&rDsr[dbase]     = make_float4(rs_[0], rs_[1], rs_[2], rs_[3]);
    *(float4*)&rDsr[dbase + 4] = make_float4(rs_[4], rs_[5], rs_[6], rs_[7]);
  }

  // pass 2: normalize + coalesced store
  for (int r = 0; r < 64; ++r){
    int m = adj_sr[n*Rc + r];
    float a[8];
    if (m){
      const float* qr = &ql[r*64];
#pragma unroll
      for (int h = 0; h < 8; ++h){
        float4 qa = *(const float4*)&qr[h*8];
        float4 qb = *(const float4*)&qr[h*8 + 4];
        float e = qa.x*kr[h*8+0] + qa.y*kr[h*8+1] + qa.z*kr[h*8+2] + qa.w*kr[h*8+3]
                + qb.x*kr[h*8+4] + qb.y*kr[h*8+5] + qb.z*kr[h*8+6] + qb.w*kr[h*8+7];
        a[h] = __expf(clip5(e*0.125f)) * rs_[h];
      }
    } else {
#pragma unroll
      for (int h = 0; h < 8; ++h) a[h] = EXPM5 * rs_[h];
    }
    size_t ao = ((size_t)((b*Rc + r)*Nc + n))*THc + t*8;  // [B][R][N][T*8+h]
    *(float4*)&o_asr[ao]     = make_float4(a[0], a[1], a[2], a[3]);
    *(float4*)&o_asr[ao + 4] = make_float4(a[4], a[5], a[6], a[7]);
  }
}

// ---------------- sr attention (PV only): block=(b,t,h) x 4 waves ---------------
// Denominators precomputed by k_asr_write; block stages its 512-float rD slice
// into LDS once (vector loads), then per-iteration reads are LDS broadcasts.
// No shuffle chains, no divides -> pure FMA/exp throughput.
__global__ __launch_bounds__(256) void k_attn_sr(
    const float* __restrict__ khat, const float* __restrict__ vhat,
    const float* __restrict__ qhat, const int* __restrict__ adj_sr,
    const float* __restrict__ rD, float* __restrict__ pre)
{
  __shared__ float accs[4][64][8];
  __shared__ float rDl[512];
  int bid = blockIdx.x;
  int b = bid >> 10, th = bid & 1023;
  int t = th >> 3, h = th & 7;
  int tid = threadIdx.x;
  int r = tid & 63, w = tid >> 6;
  rDl[tid]       = rD[((size_t)((b*Nc + tid      )*Tc + t))*8 + h];
  rDl[tid + 256] = rD[((size_t)((b*Nc + tid + 256)*Tc + t))*8 + h];
  float q[8];
#pragma unroll
  for (int d = 0; d < 8; ++d) q[d] = qhat[r*Ec + h*8 + d];
  __syncthreads();
  float acc[8] = {0,0,0,0,0,0,0,0};
  int n0 = w*128;
  for (int n = n0; n < n0 + 128; n += 2){
    size_t goA = ((size_t)((b*Nc + n)*Tc + t))*Ec + h*8;
    size_t goB = goA + (size_t)Tc*Ec;
    const float* kA = khat + goA;
    const float* kB = khat + goB;
    float eA = 0.0f, eB = 0.0f;
#pragma unroll
    for (int d = 0; d < 8; ++d){ eA += q[d]*kA[d]; eB += q[d]*kB[d]; }
    int mA = adj_sr[n*Rc + r], mB = adj_sr[(n+1)*Rc + r];
    eA = mA ? clip5(eA*0.125f) : -5.0f;
    eB = mB ? clip5(eB*0.125f) : -5.0f;
    float aA = __expf(eA) * rDl[n];
    float aB = __expf(eB) * rDl[n+1];
    const float* vA = vhat + goA;
    const float* vB = vhat + goB;
#pragma unroll
    for (int d = 0; d < 8; ++d) acc[d] += aA*vA[d] + aB*vB[d];
  }
#pragma unroll
  for (int d = 0; d < 8; ++d) accs[w][r][d] = acc[d];
  __syncthreads();
  if (w == 0){
    size_t po = ((size_t)((b*Rc + r)*Tc + t))*Ec + h*8;   // [B][R][T][E]
#pragma unroll
    for (int d = 0; d < 8; ++d)
      pre[po + d] = accs[0][r][d] + accs[1][r][d] + accs[2][r][d] + accs[3][r][d];
  }
}

// ---------------- rr attention: block=(b,t,h) x 4 waves; wave=k-chunk -----------
__global__ __launch_bounds__(256) void k_attn_rr(
    const float* __restrict__ qh, const float* __restrict__ kh,
    const float* __restrict__ vh, const int* __restrict__ adj_r,
    bf16* __restrict__ att_c, float* __restrict__ pre)
{
  __shared__ float accs[4][64][8];
  int bid = blockIdx.x;
  int b = bid >> 10, th = bid & 1023;
  int t = th >> 3, h = th & 7;
  int tid = threadIdx.x;
  int q = tid & 63, w = tid >> 6;
  size_t qo = ((size_t)((b*Rc + q)*Tc + t))*Ec + h*8;
  float qv[8];
#pragma unroll
  for (int d = 0; d < 8; ++d) qv[d] = qh[qo + d];
  float acc[8] = {0,0,0,0,0,0,0,0};
  int k0 = w*16;
  for (int k = k0; k < k0 + 16; k += 2){
    size_t koA = ((size_t)((b*Rc + k)*Tc + t))*Ec + h*8;
    size_t koB = koA + (size_t)Tc*Ec;
    const float* kA = kh + koA;
    const float* kB = kh + koB;
    float eA = 0.0f, eB = 0.0f;
#pragma unroll
    for (int d = 0; d < 8; ++d){ eA += qv[d]*kA[d]; eB += qv[d]*kB[d]; }
    int mA = adj_r[q*Rc + k], mB = adj_r[q*Rc + k + 1];
    eA = mA ? clip5(eA*0.125f) : -5.0f;
    eB = mB ? clip5(eB*0.125f) : -5.0f;
    float pA = __expf(eA), pB = __expf(eB);
    float sA = pA, sB = pB;
    wave_sum64x2(sA, sB);
    float aA = pA/sA, aB = pB/sB;
    size_t ao = ((size_t)(b*Rc + k)*THc + th)*Rc + q;
    att_c[ao] = f2b(aA);                              // [B][K][TH][Q=64]
    att_c[ao + (size_t)THc*Rc] = f2b(aB);
    const float* vA = vh + koA;
    const float* vB = vh + koB;
#pragma unroll
    for (int d = 0; d < 8; ++d) acc[d] += aA*vA[d] + aB*vB[d];
  }
#pragma unroll
  for (int d = 0; d < 8; ++d) accs[w][q][d] = acc[d];
  __syncthreads();
  if (w == 0){
#pragma unroll
    for (int d = 0; d < 8; ++d)
      pre[qo + d] = accs[0][q][d] + accs[1][q][d] + accs[2][q][d] + accs[3][q][d];
  }
}

// ---------------- rs attention: block=(b,t,h) x 512 thr, thread=q ---------------
// Two-phase, 2-barrier structure: phase 1 computes per-wave partial softmax
// denominators for ALL 64 k (4-way ILP shuffle sums, no barriers); one barrier +
// 64-thread cross-wave reduce -> redr[k]=rcp(stot); one barrier; phase 2
// recomputes dot+exp and does normalize + bf16 att store + PV.
__global__ __launch_bounds__(512) void k_attn_rs(
    const float* __restrict__ query, const float* __restrict__ ds,
    const float* __restrict__ Wq, const float* __restrict__ kh,
    const float* __restrict__ vh, bf16* __restrict__ att_c, float* __restrict__ pre)
{
  __shared__ float wq[64];
  __shared__ float kl[64][8];
  __shared__ float vl[64][8];
  __shared__ float part[8][64];
  __shared__ float redr[64];
  int bid = blockIdx.x;
  int b = bid >> 10, th = bid & 1023;
  int t = th >> 3, h = th & 7;
  int q = threadIdx.x;
  if (q < 64) wq[q] = Wq[q];
  {
    int kk = q >> 3, d = q & 7;
    size_t o = ((size_t)((b*Rc + kk)*Tc + t))*Ec + h*8 + d;
    kl[kk][d] = kh[o];
    vl[kk][d] = vh[o];
  }
  __syncthreads();
  size_t qro = ((size_t)((b*Nc + q)*Tc + t))*Ec + h*8;
  const float* dsp = ds + q*Ec + h*8;
  float xin[8], qv[8];
#pragma unroll
  for (int d = 0; d < 8; ++d) xin[d] = query[qro + d] + dsp[d];
#pragma unroll
  for (int d = 0; d < 8; ++d){
    float a = 0.0f;
#pragma unroll
    for (int d0 = 0; d0 < 8; ++d0) a += xin[d0]*wq[d0*8 + d];
    qv[d] = a;
  }
  int lane = q & 63, wv = q >> 6;
  // ---- phase 1: per-wave partial denominators for all k ----
  for (int k = 0; k < 64; k += 4){
    float s0 = 0.0f, s1 = 0.0f, s2 = 0.0f, s3 = 0.0f;
#pragma unroll
    for (int d = 0; d < 8; ++d){
      s0 += qv[d]*kl[k  ][d];
      s1 += qv[d]*kl[k+1][d];
      s2 += qv[d]*kl[k+2][d];
      s3 += qv[d]*kl[k+3][d];
    }
    s0 = __expf(clip5(s0*0.125f));
    s1 = __expf(clip5(s1*0.125f));
    s2 = __expf(clip5(s2*0.125f));
    s3 = __expf(clip5(s3*0.125f));
    wave_sum64x4(s0, s1, s2, s3);
    if (lane == 0){
      part[wv][k] = s0; part[wv][k+1] = s1; part[wv][k+2] = s2; part[wv][k+3] = s3;
    }
  }
  __syncthreads();
  if (q < 64){
    float s = 0.0f;
#pragma unroll
    for (int w2 = 0; w2 < 8; ++w2) s += part[w2][q];
    redr[q] = __builtin_amdgcn_rcpf(s);
  }
  __syncthreads();
  // ---- phase 2: normalize + att store + PV ----
  float acc[8] = {0,0,0,0,0,0,0,0};
  for (int k = 0; k < 64; k += 2){
    float eA = 0.0f, eB = 0.0f;
#pragma unroll
    for (int d = 0; d < 8; ++d){ eA += qv[d]*kl[k][d]; eB += qv[d]*kl[k+1][d]; }
    float aA = __expf(clip5(eA*0.125f)) * redr[k];
    float aB = __expf(clip5(eB*0.125f)) * redr[k+1];
    size_t ao = ((size_t)(b*Rc + k)*THc + th)*Nc + q;
    att_c[ao] = f2b(aA);                              // [B][K][TH][Q=512]
    att_c[ao + (size_t)THc*Nc] = f2b(aB);
#pragma unroll
    for (int d = 0; d < 8; ++d) acc[d] += aA*vl[k][d] + aB*vl[k+1][d];
  }
#pragma unroll
  for (int d = 0; d < 8; ++d) pre[qro + d] = acc[d];         // [B][N][T][E]
}

// ---- transpose+widen: src bf16 [B][W][TH][C] -> dst fp32 [((b*C+c)*W+w)*TH+th] --
__global__ __launch_bounds__(256) void k_transpose(
    const unsigned short* __restrict__ src, float* __restrict__ dst,
    int W, int C)
{
  __shared__ unsigned short tile[64][66];
  int bid = blockIdx.x;
  int nct = C >> 6;
  int ct = bid % nct; bid /= nct;
  int tht = bid & 15; bid >>= 4;
  int w = bid % W; int b = bid / W;
  int tt = threadIdx.x;
  {
    int cs = tt & 63, i0 = tt >> 6;
    const unsigned short* sb = src + ((size_t)(b*W + w)*THc + tht*64)*C + ct*64;
#pragma unroll
    for (int p = 0; p < 16; ++p){
      int i = i0 + p*4;
      tile[i][cs] = sb[(size_t)i*C + cs];
    }
  }
  __syncthreads();
  {
    int i = tt & 63, c0 = tt >> 6;
#pragma unroll
    for (int p = 0; p < 16; ++p){
      int cs = c0 + p*4;
      int c = ct*64 + cs;
      dst[((size_t)(b*C + c)*W + w)*THc + tht*64 + i] = us2f(tile[i][cs]);
    }
  }
}

// -------- Wo projection: wave per row, (sum of nparts partials) @ Wo + bo -------
__global__ __launch_bounds__(256) void k_wo(
    const float* __restrict__ pre, int nparts, int pstride,
    const float* __restrict__ Wo,
    const float* __restrict__ bo, float* __restrict__ outf,
    float* __restrict__ outf2, int nrows)
{
  int gt = blockIdx.x*256 + threadIdx.x;
  int row = gt >> 6, lane = gt & 63;
  if (row >= nrows) return;
  float xin = 0.0f;
  for (int p2 = 0; p2 < nparts; ++p2)
    xin += pre[(size_t)p2*pstride + (size_t)row*64 + lane];
  float acc = bo[lane];
  for (int e = 0; e < 64; ++e){
    float xe = __shfl(xin, e, 64);
    acc += xe * Wo[e*64 + lane];
  }
  outf[(size_t)row*64 + lane] = acc;
  if (outf2) outf2[(size_t)row*64 + lane] = acc;
}

// ---------------- per-head triple projection from [rows][64] fp32 ---------------
__global__ __launch_bounds__(256) void k_proj3(
    const float* __restrict__ src, const float* Wq, const float* Wk, const float* Wv,
    float* qh, float* kh, float* vh, int nunits)
{
  __shared__ float wq[64], wk[64], wv[64];
  int t = threadIdx.x;
  if (t < 64){
    wq[t] = Wq ? Wq[t] : 0.0f;
    wk[t] = Wk[t];
    wv[t] = Wv[t];
  }
  __syncthreads();
  int u = blockIdx.x*256 + t;
  if (u >= nunits) return;
  const float* sp = src + (size_t)u*8;
  float xin[8];
#pragma unroll
  for (int d = 0; d < 8; ++d) xin[d] = sp[d];
#pragma unroll
  for (int d = 0; d < 8; ++d){
    float qa = 0.0f, ka = 0.0f, va = 0.0f;
#pragma unroll
    for (int d0 = 0; d0 < 8; ++d0){
      qa += xin[d0]*wq[d0*8 + d];
      ka += xin[d0]*wk[d0*8 + d];
      va += xin[d0]*wv[d0*8 + d];
    }
    if (qh) qh[(size_t)u*8 + d] = qa;
    kh[(size_t)u*8 + d] = ka;
    vh[(size_t)u*8 + d] = va;
  }
}

// =====================================================================
// fused tail: LDS-tiled register-blocked fp32 GEMMs.
// block = 256 thr = 64 rows; thread = 4 rows x 4 cols micro-tile.
// =====================================================================
__device__ __forceinline__ void gemm64x64(
    const float (* __restrict__ Xs)[68], const float* __restrict__ W,
    int Wld, int r0, int c0, float acc[4][4])
{
#pragma unroll 4
  for (int k = 0; k < 64; k += 4){
    float4 xr0 = *(const float4*)&Xs[r0+0][k];
    float4 xr1 = *(const float4*)&Xs[r0+1][k];
    float4 xr2 = *(const float4*)&Xs[r0+2][k];
    float4 xr3 = *(const float4*)&Xs[r0+3][k];
#pragma unroll
    for (int kk = 0; kk < 4; ++kk){
      float4 w = *(const float4*)&W[(size_t)(k+kk)*Wld + c0];
      float x0 = (&xr0.x)[kk], x1 = (&xr1.x)[kk];
      float x2 = (&xr2.x)[kk], x3 = (&xr3.x)[kk];
      acc[0][0] += x0*w.x; acc[0][1] += x0*w.y; acc[0][2] += x0*w.z; acc[0][3] += x0*w.w;
      acc[1][0] += x1*w.x; acc[1][1] += x1*w.y; acc[1][2] += x1*w.z; acc[1][3] += x1*w.w;
      acc[2][0] += x2*w.x; acc[2][1] += x2*w.y; acc[2][2] += x2*w.z; acc[2][3] += x2*w.w;
      acc[3][0] += x3*w.x; acc[3][1] += x3*w.y; acc[3][2] += x3*w.z; acc[3][3] += x3*w.w;
    }
  }
}

// per-row LN on the 4x4 tile (row spread across 16 lanes)
__device__ __forceinline__ void ln64(
    const float acc[4][4], float4 g, float4 b, float out[4][4])
{
#pragma unroll
  for (int i = 0; i < 4; ++i){
    float s = acc[i][0] + acc[i][1] + acc[i][2] + acc[i][3];
    float m = rowred16_sum(s) * (1.0f/64.0f);
    float d0 = acc[i][0] - m, d1 = acc[i][1] - m, d2 = acc[i][2] - m, d3 = acc[i][3] - m;
    float vv = d0*d0 + d1*d1 + d2*d2 + d3*d3;
    float var = rowred16_sum(vv) * (1.0f/64.0f);
    float rs = rsqrtf(var + 1e-5f);
    out[i][0] = d0*rs*g.x + b.x;
    out[i][1] = d1*rs*g.y + b.y;
    out[i][2] = d2*rs*g.z + b.z;
    out[i][3] = d3*rs*g.w + b.w;
  }
}

__global__ __launch_bounds__(256) void k_tail(
    const float* __restrict__ pre3, const float* __restrict__ query,
    const float* __restrict__ ds,
    const float* __restrict__ Wo, const float* __restrict__ bo,
    const float* __restrict__ g1, const float* __restrict__ be1,
    const float* __restrict__ W1, const float* __restrict__ b1,
    const float* __restrict__ W2, const float* __restrict__ b2,
    const float* __restrict__ g2, const float* __restrict__ be2,
    const float* __restrict__ Wfs, const float* __restrict__ bfs,
    float* __restrict__ outp)
{
  __shared__ float Xs[64][68];
  __shared__ float Hs[64][68];
  int tid = threadIdx.x;
  int cg = tid & 15, rg = tid >> 4;
  int r0 = rg*4, c0 = cg*4;
  int row_base = blockIdx.x * 64;            // 64 rows/block; T=128 -> n const/block
  int n = (row_base >> 7) & (Nc - 1);

  // stage pre3 tile into LDS
#pragma unroll
  for (int i = 0; i < 4; ++i){
    float4 t = *(const float4*)&pre3[(size_t)(row_base + r0 + i)*64 + c0];
    *(float4*)&Xs[r0+i][c0] = t;
  }

  float4 bo4  = *(const float4*)&bo[c0];
  float4 ds4  = *(const float4*)&ds[n*64 + c0];
  float4 g14  = *(const float4*)&g1[c0];
  float4 be14 = *(const float4*)&be1[c0];
  float4 b24  = *(const float4*)&b2[c0];
  float4 g24  = *(const float4*)&g2[c0];
  float4 be24 = *(const float4*)&be2[c0];
  float4 bfs4 = *(const float4*)&bfs[c0];
  __syncthreads();

  // ---- attn = pre3 @ Wo + bo ; v0 = attn + (query + ds) ; x = LN1(v0) ----
  float acc[4][4];
#pragma unroll
  for (int i = 0; i < 4; ++i){
    acc[i][0] = bo4.x; acc[i][1] = bo4.y; acc[i][2] = bo4.z; acc[i][3] = bo4.w;
  }
  gemm64x64(Xs, Wo, 64, r0, c0, acc);
#pragma unroll
  for (int i = 0; i < 4; ++i){
    float4 qv = *(const float4*)&query[(size_t)(row_base + r0 + i)*64 + c0];
    acc[i][0] += qv.x + ds4.x;
    acc[i][1] += qv.y + ds4.y;
    acc[i][2] += qv.z + ds4.z;
    acc[i][3] += qv.w + ds4.w;
  }
  float xt[4][4];
  ln64(acc, g14, be14, xt);
  __syncthreads();                 // all Wo-GEMM reads of Xs complete
#pragma unroll
  for (int i = 0; i < 4; ++i)
    *(float4*)&Xs[r0+i][c0] = make_float4(xt[i][0], xt[i][1], xt[i][2], xt[i][3]);
  __syncthreads();                 // Xs now holds x

  // ---- ff = relu(x @ W1 + b1) @ W2 + b2, in 4 panels of 64 hidden cols ----
  float ff[4][4];
#pragma unroll
  for (int i = 0; i < 4; ++i){
    ff[i][0] = b24.x; ff[i][1] = b24.y; ff[i][2] = b24.z; ff[i][3] = b24.w;
  }
  for (int p = 0; p < 4; ++p){
    float4 b14 = *(const float4*)&b1[p*64 + c0];
    float h[4][4];
#pragma unroll
    for (int i = 0; i < 4; ++i){
      h[i][0] = b14.x; h[i][1] = b14.y; h[i][2] = b14.z; h[i][3] = b14.w;
    }
    gemm64x64(Xs, W1 + p*64, 256, r0, c0, h);
#pragma unroll
    for (int i = 0; i < 4; ++i){
      h[i][0] = fmaxf(h[i][0], 0.0f); h[i][1] = fmaxf(h[i][1], 0.0f);
      h[i][2] = fmaxf(h[i][2], 0.0f); h[i][3] = fmaxf(h[i][3], 0.0f);
    }
    __syncthreads();               // prev panel's FF2 reads of Hs complete
#pragma unroll
    for (int i = 0; i < 4; ++i)
      *(float4*)&Hs[r0+i][c0] = make_float4(h[i][0], h[i][1], h[i][2], h[i][3]);
    __syncthreads();               // Hs holds hidden panel
    gemm64x64(Hs, W2 + (size_t)p*64*64, 64, r0, c0, ff);
  }

  // ---- u0 = ff + x ; U = LN2(u0) ----
#pragma unroll
  for (int i = 0; i < 4; ++i){
    float4 xv = *(const float4*)&Xs[r0+i][c0];
    ff[i][0] += xv.x; ff[i][1] += xv.y; ff[i][2] += xv.z; ff[i][3] += xv.w;
  }
  float U[4][4];
  ln64(ff, g24, be24, U);
  __syncthreads();                 // last FF2 reads of Hs complete
#pragma unroll
  for (int i = 0; i < 4; ++i)
    *(float4*)&Hs[r0+i][c0] = make_float4(U[i][0], U[i][1], U[i][2], U[i][3]);
  __syncthreads();                 // Hs holds U

  // ---- out = U @ Wfs + bfs ----
  float o[4][4];
#pragma unroll
  for (int i = 0; i < 4; ++i){
    o[i][0] = bfs4.x; o[i][1] = bfs4.y; o[i][2] = bfs4.z; o[i][3] = bfs4.w;
  }
  gemm64x64(Hs, Wfs, 64, r0, c0, o);
#pragma unroll
  for (int i = 0; i < 4; ++i)
    *(float4*)&outp[(size_t)(row_base + r0 + i)*64 + c0] =
        make_float4(o[i][0], o[i][1], o[i][2], o[i][3]);
}

extern "C" void kernel_launch(void* const* d_in, const int* in_sizes, int n_in,
                              void* d_out, int out_size, void* d_ws, size_t ws_size,
                              hipStream_t stream)
{
  const float* value = (const float*)d_in[0];
  const float* key   = (const float*)d_in[1];
  const float* query = (const float*)d_in[2];
  const int*  adj_sr = (const int*)d_in[3];
  const int*  adj_r  = (const int*)d_in[4];
  const float* D_S   = (const float*)d_in[5];
  const float* W_emb = (const float*)d_in[6];
  const float* b_emb = (const float*)d_in[7];
  const float* I_par = (const float*)d_in[8];
  const float* g1    = (const float*)d_in[9];
  const float* be1   = (const float*)d_in[10];
  const float* g2    = (const float*)d_in[11];
  const float* be2   = (const float*)d_in[12];
  const float* W_ff1 = (const float*)d_in[13];
  const float* b_ff1 = (const float*)d_in[14];
  const float* W_ff2 = (const float*)d_in[15];
  const float* b_ff2 = (const float*)d_in[16];
  const float* W_fs  = (const float*)d_in[17];
  const float* b_fs  = (const float*)d_in[18];
  const float* Wv_sr = (const float*)d_in[19];
  const float* Wk_sr = (const float*)d_in[20];
  const float* Wq_sr = (const float*)d_in[21];
  const float* Wo_sr = (const float*)d_in[22];
  const float* bo_sr = (const float*)d_in[23];
  const float* Wv_rr = (const float*)d_in[24];
  const float* Wk_rr = (const float*)d_in[25];
  const float* Wq_rr = (const float*)d_in[26];
  const float* Wo_rr = (const float*)d_in[27];
  const float* bo_rr = (const float*)d_in[28];
  const float* Wv_rs = (const float*)d_in[29];
  const float* Wk_rs = (const float*)d_in[30];
  const float* Wq_rs = (const float*)d_in[31];
  const float* Wo_rs = (const float*)d_in[32];
  const float* bo_rs = (const float*)d_in[33];

  float* outp  = (float*)d_out;
  float* o_out = outp;
  float* o_asr = outp + 8388608;
  float* o_arr = outp + 75497472;
  float* o_ars = outp + 83886080;
  float* o_hh  = outp + 150994944;

  // ---- workspace overlay (lifetime-checked) ----
  float* wsf = (float*)d_ws;
  float* ws_ds   = wsf;                      // 32768 floats, persistent
  float* ws_qsr  = wsf + 32768;              // 4096
  bf16*  ws_att  = (bf16*)(wsf + 36864);     // bf16 att scratch (rr + rs stages)
  float* ws_rDsr = wsf + 36864;              // aliases ws_att head; stage-1 only,
                                             // dead before rr/rs att use. 1M floats
  float* pool    = wsf + 36864 + 33554432;   // stage-local scratch pool
  // stage 1
  float* ws_ksr  = pool;                     // 8,388,608
  float* ws_vsr  = pool + 8388608;           // 8,388,608
  float* ws_pre1 = pool + 16777216;          // 1,048,576
  float* ws_hh1  = pool + 17825792;          // 1,048,576
  // stage 2 (ksr/vsr dead by now)
  float* ws_qrr  = pool;                     // 1,048,576
  float* ws_krr  = pool + 1048576;
  float* ws_vrr  = pool + 2097152;
  float* ws_pre2 = pool + 3145728;
  float* ws_hh2  = pool + 4194304;
  // stage 3
  float* ws_krs  = pool + 5242880;
  float* ws_vrs  = pool + 6291456;
  float* ws_pre3 = pool + 7340032;           // 8,388,608

  // ---- stage 1: sr attention (denominator+asr writer first, then PV) ----
  k_prep<<<576, 64, 0, stream>>>(D_S, W_emb, b_emb, I_par, Wq_sr, ws_ds, ws_qsr);
  k_proj_sr<<<4096, 256, 0, stream>>>(key, value, ws_ds, Wk_sr, Wv_sr, ws_ksr, ws_vsr);
  k_asr_write<<<512, 256, 0, stream>>>(ws_ksr, ws_qsr, adj_sr, o_asr, ws_rDsr);
  k_attn_sr<<<2048, 256, 0, stream>>>(ws_ksr, ws_vsr, ws_qsr, adj_sr,
                                      ws_rDsr, ws_pre1);
  k_wo<<<4096, 256, 0, stream>>>(ws_pre1, 1, 0, Wo_sr, bo_sr,
                                 ws_hh1, (float*)nullptr, 16384);

  // ---- stage 2: rr attention ----
  k_proj3<<<512, 256, 0, stream>>>(ws_hh1, Wq_rr, Wk_rr, Wv_rr,
                                   ws_qrr, ws_krr, ws_vrr, 131072);
  k_attn_rr<<<2048, 256, 0, stream>>>(ws_qrr, ws_krr, ws_vrr, adj_r, ws_att, ws_pre2);
  k_transpose<<<2048, 256, 0, stream>>>((const unsigned short*)ws_att, o_arr, 64, 64);
  k_wo<<<4096, 256, 0, stream>>>(ws_pre2, 1, 0, Wo_rr, bo_rr, ws_hh2, o_hh, 16384);

  // ---- stage 3: rs attention ----
  k_proj3<<<512, 256, 0, stream>>>(ws_hh2, (const float*)nullptr, Wk_rs, Wv_rs,
                                   (float*)nullptr, ws_krs, ws_vrs, 131072);
  k_attn_rs<<<2048, 512, 0, stream>>>(query, ws_ds, Wq_rs, ws_krs, ws_vrs,
                                      ws_att, ws_pre3);
  k_transpose<<<16384, 256, 0, stream>>>((const unsigned short*)ws_att, o_ars, 64, 512);

  // ---- tail: Wo_rs + LN + FF + LN + W_fs (fused, LDS-tiled fp32 GEMM) ----
  k_tail<<<2048, 256, 0, stream>>>(ws_pre3, query, ws_ds, Wo_rs, bo_rs,
                                   g1, be1, W_ff1, b_ff1, W_ff2, b_ff2,
                                   g2, be2, W_fs, b_fs, o_out);
}

// Round 8
// 816.238 us; speedup vs baseline: 1.2676x; 1.0477x over previous
//
#include <hip/hip_runtime.h>
#include <hip/hip_bf16.h>

typedef __hip_bfloat16 bf16;

#define Bc 2
#define Nc 512
#define Rc 64
#define Tc 128
#define Ec 64
#define Hc 8
#define THc 1024
#define FFc 256

__device__ __forceinline__ bf16  f2b(float x){ return __float2bfloat16(x); }
__device__ __forceinline__ float us2f(unsigned short u){
  union { unsigned int i; float f; } c; c.i = ((unsigned int)u) << 16; return c.f;
}
__device__ __forceinline__ float clip5(float x){ return fminf(fmaxf(x, -5.0f), 5.0f); }

// two interleaved wave sums (ILP across the serial shuffle chain)
__device__ __forceinline__ void wave_sum64x2(float& a, float& b){
#pragma unroll
  for (int o = 32; o > 0; o >>= 1){
    a += __shfl_xor(a, o, 64);
    b += __shfl_xor(b, o, 64);
  }
}
// four interleaved wave sums
__device__ __forceinline__ void wave_sum64x4(float& a, float& b, float& c, float& d){
#pragma unroll
  for (int o = 32; o > 0; o >>= 1){
    a += __shfl_xor(a, o, 64);
    b += __shfl_xor(b, o, 64);
    c += __shfl_xor(c, o, 64);
    d += __shfl_xor(d, o, 64);
  }
}

// sum across the 16 lanes that co-own one row (lanes are 16-aligned groups)
__device__ __forceinline__ float rowred16_sum(float v){
  v += __shfl_xor(v, 1, 64);
  v += __shfl_xor(v, 2, 64);
  v += __shfl_xor(v, 4, 64);
  v += __shfl_xor(v, 8, 64);
  return v;
}

// ---------------- prep: ds = D_S@W_emb + b_emb ; qhat_sr = I_param(head)@Wq_sr ----
__global__ __launch_bounds__(64) void k_prep(
    const float* __restrict__ DS, const float* __restrict__ Wemb,
    const float* __restrict__ bemb, const float* __restrict__ Ip,
    const float* __restrict__ Wq, float* __restrict__ ds, float* __restrict__ qhat)
{
  int bid = blockIdx.x, t = threadIdx.x;
  if (bid < Nc){
    int n = bid, e = t;
    __shared__ float row[Rc];
    row[t] = DS[n*Rc + t];
    __syncthreads();
    float acc = bemb[e];
    for (int r = 0; r < Rc; ++r) acc += row[r] * Wemb[r*Ec + e];
    ds[n*Ec + e] = acc;
  } else {
    int r = bid - Nc;
    __shared__ float irow[Ec];
    irow[t] = Ip[r*Ec + t];
    __syncthreads();
    int h = t >> 3, d = t & 7;
    float acc = 0.0f;
#pragma unroll
    for (int d0 = 0; d0 < 8; ++d0) acc += irow[h*8 + d0] * Wq[d0*8 + d];
    qhat[r*Ec + h*8 + d] = acc;   // [R][H][D]
  }
}

// ---------------- khat_sr = (key+ds)@Wk per head; vhat_sr = value@Wv --------------
__global__ __launch_bounds__(256) void k_proj_sr(
    const float* __restrict__ key, const float* __restrict__ value,
    const float* __restrict__ ds, const float* __restrict__ Wk,
    const float* __restrict__ Wv, float* __restrict__ khat, float* __restrict__ vhat)
{
  __shared__ float wk[64], wv[64];
  int t = threadIdx.x;
  if (t < 64){ wk[t] = Wk[t]; wv[t] = Wv[t]; }
  __syncthreads();
  int u = blockIdx.x*256 + t;              // (b,n,t,h) unit, < 1048576
  int h = u & 7;
  int nt = u >> 3;                         // (b*N+n)*T + t
  int n = (nt / Tc) % Nc;
  const float* kp = key + (size_t)u*8;
  const float* vp = value + (size_t)u*8;
  const float* dsp = ds + n*Ec + h*8;
  float kin[8], vin[8];
#pragma unroll
  for (int d = 0; d < 8; ++d){ kin[d] = kp[d] + dsp[d]; vin[d] = vp[d]; }
  float* ko = khat + (size_t)u*8;
  float* vo = vhat + (size_t)u*8;
#pragma unroll
  for (int d = 0; d < 8; ++d){
    float ka = 0.0f, va = 0.0f;
#pragma unroll
    for (int d0 = 0; d0 < 8; ++d0){ ka += kin[d0]*wk[d0*8+d]; va += vin[d0]*wv[d0*8+d]; }
    ko[d] = ka; vo[d] = va;
  }
}

// ---------------- asr writer: lane = t -> fully coalesced fp32 asr --------------
// block = (b, n-pair), 256 thr: n = n0 + (tid>>7), t = tid&127.
// Softmax denominator over r is in-thread (no shuffles). Also emits the
// reciprocal denominators rDsr[b][n][t][h] for k_attn_sr to reuse.
__global__ __launch_bounds__(256) void k_asr_write(
    const float* __restrict__ khat, const float* __restrict__ qhat,
    const int* __restrict__ adj_sr, float* __restrict__ o_asr,
    float* __restrict__ rDsr)
{
  __shared__ float ql[4096];                 // q [r][h*8+d]
  const float EXPM5 = 0.006737946999085467f; // exp(-5)
  int bid = blockIdx.x;                      // b*256 + npair
  int b = bid >> 8, np = bid & 255;
  int tid = threadIdx.x;
  int n = np*2 + (tid >> 7);
  int t = tid & 127;
#pragma unroll
  for (int i = 0; i < 16; ++i) ql[i*256 + tid] = qhat[i*256 + tid];
  __syncthreads();
  const float* kp = khat + ((size_t)((b*Nc + n)*Tc + t))*Ec;
  float kr[64];
#pragma unroll
  for (int i = 0; i < 16; ++i) *(float4*)&kr[i*4] = *(const float4*)&kp[i*4];

  // pass 1: denominators s[h] = sum_r exp(e[r][h])
  float s[8] = {0,0,0,0,0,0,0,0};
  for (int r = 0; r < 64; ++r){
    int m = adj_sr[n*Rc + r];                // wave-uniform
    if (m){
      const float* qr = &ql[r*64];
#pragma unroll
      for (int h = 0; h < 8; ++h){
        float4 qa = *(const float4*)&qr[h*8];
        float4 qb = *(const float4*)&qr[h*8 + 4];
        float e = qa.x*kr[h*8+0] + qa.y*kr[h*8+1] + qa.z*kr[h*8+2] + qa.w*kr[h*8+3]
                + qb.x*kr[h*8+4] + qb.y*kr[h*8+5] + qb.z*kr[h*8+6] + qb.w*kr[h*8+7];
        s[h] += __expf(clip5(e*0.125f));
      }
    } else {
#pragma unroll
      for (int h = 0; h < 8; ++h) s[h] += EXPM5;
    }
  }
  float rs_[8];
#pragma unroll
  for (int h = 0; h < 8; ++h) rs_[h] = __builtin_amdgcn_rcpf(s[h]);
  {
    size_t dbase = ((size_t)((b*Nc + n)*Tc + t))*8;   // [B][N][T][H]
    *(float4*)&rDsr[dbase]     = make_float4(rs_[0], rs_[1], rs_[2], rs_[3]);
    *(float4*)&rDsr[dbase + 4] = make_float4(rs_[4], rs_[5], rs_[6], rs_[7]);
  }

  // pass 2: normalize + coalesced store
  for (int r = 0; r < 64; ++r){
    int m = adj_sr[n*Rc + r];
    float a[8];
    if (m){
      const float* qr = &ql[r*64];
#pragma unroll
      for (int h = 0; h < 8; ++h){
        float4 qa = *(const float4*)&qr[h*8];
        float4 qb = *(const float4*)&qr[h*8 + 4];
        float e = qa.x*kr[h*8+0] + qa.y*kr[h*8+1] + qa.z*kr[h*8+2] + qa.w*kr[h*8+3]
                + qb.x*kr[h*8+4] + qb.y*kr[h*8+5] + qb.z*kr[h*8+6] + qb.w*kr[h*8+7];
        a[h] = __expf(clip5(e*0.125f)) * rs_[h];
      }
    } else {
#pragma unroll
      for (int h = 0; h < 8; ++h) a[h] = EXPM5 * rs_[h];
    }
    size_t ao = ((size_t)((b*Rc + r)*Nc + n))*THc + t*8;  // [B][R][N][T*8+h]
    *(float4*)&o_asr[ao]     = make_float4(a[0], a[1], a[2], a[3]);
    *(float4*)&o_asr[ao + 4] = make_float4(a[4], a[5], a[6], a[7]);
  }
}

// ---------------- sr attention (PV only): block=(b,t,h) x 4 waves ---------------
// Denominators precomputed by k_asr_write; block stages its 512-float rD slice
// into LDS once (vector loads), then per-iteration reads are LDS broadcasts.
__global__ __launch_bounds__(256) void k_attn_sr(
    const float* __restrict__ khat, const float* __restrict__ vhat,
    const float* __restrict__ qhat, const int* __restrict__ adj_sr,
    const float* __restrict__ rD, float* __restrict__ pre)
{
  __shared__ float accs[4][64][8];
  __shared__ float rDl[512];
  int bid = blockIdx.x;
  int b = bid >> 10, th = bid & 1023;
  int t = th >> 3, h = th & 7;
  int tid = threadIdx.x;
  int r = tid & 63, w = tid >> 6;
  rDl[tid]       = rD[((size_t)((b*Nc + tid      )*Tc + t))*8 + h];
  rDl[tid + 256] = rD[((size_t)((b*Nc + tid + 256)*Tc + t))*8 + h];
  float q[8];
#pragma unroll
  for (int d = 0; d < 8; ++d) q[d] = qhat[r*Ec + h*8 + d];
  __syncthreads();
  float acc[8] = {0,0,0,0,0,0,0,0};
  int n0 = w*128;
  for (int n = n0; n < n0 + 128; n += 2){
    size_t goA = ((size_t)((b*Nc + n)*Tc + t))*Ec + h*8;
    size_t goB = goA + (size_t)Tc*Ec;
    const float* kA = khat + goA;
    const float* kB = khat + goB;
    float eA = 0.0f, eB = 0.0f;
#pragma unroll
    for (int d = 0; d < 8; ++d){ eA += q[d]*kA[d]; eB += q[d]*kB[d]; }
    int mA = adj_sr[n*Rc + r], mB = adj_sr[(n+1)*Rc + r];
    eA = mA ? clip5(eA*0.125f) : -5.0f;
    eB = mB ? clip5(eB*0.125f) : -5.0f;
    float aA = __expf(eA) * rDl[n];
    float aB = __expf(eB) * rDl[n+1];
    const float* vA = vhat + goA;
    const float* vB = vhat + goB;
#pragma unroll
    for (int d = 0; d < 8; ++d) acc[d] += aA*vA[d] + aB*vB[d];
  }
#pragma unroll
  for (int d = 0; d < 8; ++d) accs[w][r][d] = acc[d];
  __syncthreads();
  if (w == 0){
    size_t po = ((size_t)((b*Rc + r)*Tc + t))*Ec + h*8;   // [B][R][T][E]
#pragma unroll
    for (int d = 0; d < 8; ++d)
      pre[po + d] = accs[0][r][d] + accs[1][r][d] + accs[2][r][d] + accs[3][r][d];
  }
}

// ---------------- rr attention: block=(b,t,h) x 4 waves; wave=k-chunk -----------
__global__ __launch_bounds__(256) void k_attn_rr(
    const float* __restrict__ qh, const float* __restrict__ kh,
    const float* __restrict__ vh, const int* __restrict__ adj_r,
    bf16* __restrict__ att_c, float* __restrict__ pre)
{
  __shared__ float accs[4][64][8];
  int bid = blockIdx.x;
  int b = bid >> 10, th = bid & 1023;
  int t = th >> 3, h = th & 7;
  int tid = threadIdx.x;
  int q = tid & 63, w = tid >> 6;
  size_t qo = ((size_t)((b*Rc + q)*Tc + t))*Ec + h*8;
  float qv[8];
#pragma unroll
  for (int d = 0; d < 8; ++d) qv[d] = qh[qo + d];
  float acc[8] = {0,0,0,0,0,0,0,0};
  int k0 = w*16;
  for (int k = k0; k < k0 + 16; k += 2){
    size_t koA = ((size_t)((b*Rc + k)*Tc + t))*Ec + h*8;
    size_t koB = koA + (size_t)Tc*Ec;
    const float* kA = kh + koA;
    const float* kB = kh + koB;
    float eA = 0.0f, eB = 0.0f;
#pragma unroll
    for (int d = 0; d < 8; ++d){ eA += qv[d]*kA[d]; eB += qv[d]*kB[d]; }
    int mA = adj_r[q*Rc + k], mB = adj_r[q*Rc + k + 1];
    eA = mA ? clip5(eA*0.125f) : -5.0f;
    eB = mB ? clip5(eB*0.125f) : -5.0f;
    float pA = __expf(eA), pB = __expf(eB);
    float sA = pA, sB = pB;
    wave_sum64x2(sA, sB);
    float aA = pA/sA, aB = pB/sB;
    size_t ao = ((size_t)(b*Rc + k)*THc + th)*Rc + q;
    att_c[ao] = f2b(aA);                              // [B][K][TH][Q=64]
    att_c[ao + (size_t)THc*Rc] = f2b(aB);
    const float* vA = vh + koA;
    const float* vB = vh + koB;
#pragma unroll
    for (int d = 0; d < 8; ++d) acc[d] += aA*vA[d] + aB*vB[d];
  }
#pragma unroll
  for (int d = 0; d < 8; ++d) accs[w][q][d] = acc[d];
  __syncthreads();
  if (w == 0){
#pragma unroll
    for (int d = 0; d < 8; ++d)
      pre[qo + d] = accs[0][q][d] + accs[1][q][d] + accs[2][q][d] + accs[3][q][d];
  }
}

// ------ rs attention (PV + denominators): block=(b,t,h) x 512 thr, thread=q -----
// Two-phase, 2-barrier structure; no att-tensor write. Emits reciprocal
// denominators rDrs[b][k][t][h] for the coalesced ars writer.
__global__ __launch_bounds__(512) void k_attn_rs(
    const float* __restrict__ query, const float* __restrict__ ds,
    const float* __restrict__ Wq, const float* __restrict__ kh,
    const float* __restrict__ vh, float* __restrict__ rDrs,
    float* __restrict__ pre)
{
  __shared__ float wq[64];
  __shared__ float kl[64][8];
  __shared__ float vl[64][8];
  __shared__ float part[8][64];
  __shared__ float redr[64];
  int bid = blockIdx.x;
  int b = bid >> 10, th = bid & 1023;
  int t = th >> 3, h = th & 7;
  int q = threadIdx.x;
  if (q < 64) wq[q] = Wq[q];
  {
    int kk = q >> 3, d = q & 7;
    size_t o = ((size_t)((b*Rc + kk)*Tc + t))*Ec + h*8 + d;
    kl[kk][d] = kh[o];
    vl[kk][d] = vh[o];
  }
  __syncthreads();
  size_t qro = ((size_t)((b*Nc + q)*Tc + t))*Ec + h*8;
  const float* dsp = ds + q*Ec + h*8;
  float xin[8], qv[8];
#pragma unroll
  for (int d = 0; d < 8; ++d) xin[d] = query[qro + d] + dsp[d];
#pragma unroll
  for (int d = 0; d < 8; ++d){
    float a = 0.0f;
#pragma unroll
    for (int d0 = 0; d0 < 8; ++d0) a += xin[d0]*wq[d0*8 + d];
    qv[d] = a;
  }
  int lane = q & 63, wv = q >> 6;
  // ---- phase 1: per-wave partial denominators for all k ----
  for (int k = 0; k < 64; k += 4){
    float s0 = 0.0f, s1 = 0.0f, s2 = 0.0f, s3 = 0.0f;
#pragma unroll
    for (int d = 0; d < 8; ++d){
      s0 += qv[d]*kl[k  ][d];
      s1 += qv[d]*kl[k+1][d];
      s2 += qv[d]*kl[k+2][d];
      s3 += qv[d]*kl[k+3][d];
    }
    s0 = __expf(clip5(s0*0.125f));
    s1 = __expf(clip5(s1*0.125f));
    s2 = __expf(clip5(s2*0.125f));
    s3 = __expf(clip5(s3*0.125f));
    wave_sum64x4(s0, s1, s2, s3);
    if (lane == 0){
      part[wv][k] = s0; part[wv][k+1] = s1; part[wv][k+2] = s2; part[wv][k+3] = s3;
    }
  }
  __syncthreads();
  if (q < 64){
    float s = 0.0f;
#pragma unroll
    for (int w2 = 0; w2 < 8; ++w2) s += part[w2][q];
    float r_ = __builtin_amdgcn_rcpf(s);
    redr[q] = r_;
    rDrs[((size_t)((b*Rc + q)*Tc + t))*8 + h] = r_;   // [B][K][T][H]
  }
  __syncthreads();
  // ---- phase 2: PV with broadcast denominators ----
  float acc[8] = {0,0,0,0,0,0,0,0};
  for (int k = 0; k < 64; k += 2){
    float eA = 0.0f, eB = 0.0f;
#pragma unroll
    for (int d = 0; d < 8; ++d){ eA += qv[d]*kl[k][d]; eB += qv[d]*kl[k+1][d]; }
    float aA = __expf(clip5(eA*0.125f)) * redr[k];
    float aB = __expf(clip5(eB*0.125f)) * redr[k+1];
#pragma unroll
    for (int d = 0; d < 8; ++d) acc[d] += aA*vl[k][d] + aB*vl[k+1][d];
  }
#pragma unroll
  for (int d = 0; d < 8; ++d) pre[qro + d] = acc[d];         // [B][N][T][E]
}

// ---------------- ars writer v2: fully coalesced on ALL streams -----------------
// block = (b, qg of 8, tblk of 64): 512 thr, lane = dt*8 + h (h minor).
// For fixed (q,k): the 512 threads cover t*8+h -> 2KB contiguous store.
// kh load kh[k][t][h*8+d]: h-lanes adjacent -> 2KB contiguous per wave-group,
// L2-resident (kh_rs = 4MB). qv recomputed in-regs (Wq is per-head 8x8).
__global__ __launch_bounds__(512) void k_ars_write(
    const float* __restrict__ query, const float* __restrict__ ds,
    const float* __restrict__ Wq, const float* __restrict__ kh,
    const float* __restrict__ rD, float* __restrict__ o_ars)
{
  __shared__ float wq[64];
  int bid = blockIdx.x;
  int tblk = bid & 1; int qg = (bid >> 1) & 63; int b = bid >> 7;
  int tid = threadIdx.x;
  int dt = tid >> 3, h = tid & 7;
  int t = tblk*64 + dt;
  if (tid < 64) wq[tid] = Wq[tid];
  __syncthreads();
  float qv[8][8];
#pragma unroll
  for (int qi = 0; qi < 8; ++qi){
    int q = qg*8 + qi;
    const float* qp = query + ((size_t)((b*Nc + q)*Tc + t))*Ec + h*8;
    const float* dp = ds + q*Ec + h*8;
    float xin[8];
#pragma unroll
    for (int d = 0; d < 8; ++d) xin[d] = qp[d] + dp[d];
#pragma unroll
    for (int d = 0; d < 8; ++d){
      float a = 0.0f;
#pragma unroll
      for (int d0 = 0; d0 < 8; ++d0) a += xin[d0]*wq[d0*8 + d];
      qv[qi][d] = a;
    }
  }
  size_t qbase = ((size_t)(b*Nc + qg*8)*Rc)*THc + t*8 + h;   // [B][Q][K][T*8+h]
  for (int k = 0; k < 64; ++k){
    const float* kp = kh + ((size_t)((b*Rc + k)*Tc + t))*Ec + h*8;
    float khr[8];
#pragma unroll
    for (int d = 0; d < 8; ++d) khr[d] = kp[d];
    float rd = rD[((size_t)((b*Rc + k)*Tc + t))*8 + h];
#pragma unroll
    for (int qi = 0; qi < 8; ++qi){
      float e = 0.0f;
#pragma unroll
      for (int d = 0; d < 8; ++d) e += qv[qi][d]*khr[d];
      float a = __expf(clip5(e*0.125f)) * rd;
      o_ars[qbase + (size_t)qi*Rc*THc + (size_t)k*THc] = a;
    }
  }
}

// ---- transpose+widen: src bf16 [B][W][TH][C] -> dst fp32 [((b*C+c)*W+w)*TH+th] --
__global__ __launch_bounds__(256) void k_transpose(
    const unsigned short* __restrict__ src, float* __restrict__ dst,
    int W, int C)
{
  __shared__ unsigned short tile[64][66];
  int bid = blockIdx.x;
  int nct = C >> 6;
  int ct = bid % nct; bid /= nct;
  int tht = bid & 15; bid >>= 4;
  int w = bid % W; int b = bid / W;
  int tt = threadIdx.x;
  {
    int cs = tt & 63, i0 = tt >> 6;
    const unsigned short* sb = src + ((size_t)(b*W + w)*THc + tht*64)*C + ct*64;
#pragma unroll
    for (int p = 0; p < 16; ++p){
      int i = i0 + p*4;
      tile[i][cs] = sb[(size_t)i*C + cs];
    }
  }
  __syncthreads();
  {
    int i = tt & 63, c0 = tt >> 6;
#pragma unroll
    for (int p = 0; p < 16; ++p){
      int cs = c0 + p*4;
      int c = ct*64 + cs;
      dst[((size_t)(b*C + c)*W + w)*THc + tht*64 + i] = us2f(tile[i][cs]);
    }
  }
}

// ---------------- GEMM micro-kernel shared by k_wo / k_tail ---------------------
__device__ __forceinline__ void gemm64x64(
    const float (* __restrict__ Xs)[68], const float* __restrict__ W,
    int Wld, int r0, int c0, float acc[4][4])
{
#pragma unroll 4
  for (int k = 0; k < 64; k += 4){
    float4 xr0 = *(const float4*)&Xs[r0+0][k];
    float4 xr1 = *(const float4*)&Xs[r0+1][k];
    float4 xr2 = *(const float4*)&Xs[r0+2][k];
    float4 xr3 = *(const float4*)&Xs[r0+3][k];
#pragma unroll
    for (int kk = 0; kk < 4; ++kk){
      float4 w = *(const float4*)&W[(size_t)(k+kk)*Wld + c0];
      float x0 = (&xr0.x)[kk], x1 = (&xr1.x)[kk];
      float x2 = (&xr2.x)[kk], x3 = (&xr3.x)[kk];
      acc[0][0] += x0*w.x; acc[0][1] += x0*w.y; acc[0][2] += x0*w.z; acc[0][3] += x0*w.w;
      acc[1][0] += x1*w.x; acc[1][1] += x1*w.y; acc[1][2] += x1*w.z; acc[1][3] += x1*w.w;
      acc[2][0] += x2*w.x; acc[2][1] += x2*w.y; acc[2][2] += x2*w.z; acc[2][3] += x2*w.w;
      acc[3][0] += x3*w.x; acc[3][1] += x3*w.y; acc[3][2] += x3*w.z; acc[3][3] += x3*w.w;
    }
  }
}

// -------- Wo projection as LDS-tiled GEMM: block = 64 rows, 4x4 micro-tile ------
__global__ __launch_bounds__(256) void k_wo(
    const float* __restrict__ pre, const float* __restrict__ Wo,
    const float* __restrict__ bo, float* __restrict__ outf,
    float* __restrict__ outf2)
{
  __shared__ float Xs[64][68];
  int tid = threadIdx.x;
  int cg = tid & 15, rg = tid >> 4;
  int r0 = rg*4, c0 = cg*4;
  int row_base = blockIdx.x * 64;
#pragma unroll
  for (int i = 0; i < 4; ++i)
    *(float4*)&Xs[r0+i][c0] = *(const float4*)&pre[(size_t)(row_base + r0 + i)*64 + c0];
  float4 bo4 = *(const float4*)&bo[c0];
  __syncthreads();
  float acc[4][4];
#pragma unroll
  for (int i = 0; i < 4; ++i){
    acc[i][0] = bo4.x; acc[i][1] = bo4.y; acc[i][2] = bo4.z; acc[i][3] = bo4.w;
  }
  gemm64x64(Xs, Wo, 64, r0, c0, acc);
#pragma unroll
  for (int i = 0; i < 4; ++i){
    float4 v = make_float4(acc[i][0], acc[i][1], acc[i][2], acc[i][3]);
    *(float4*)&outf[(size_t)(row_base + r0 + i)*64 + c0] = v;
    if (outf2) *(float4*)&outf2[(size_t)(row_base + r0 + i)*64 + c0] = v;
  }
}

// ---------------- per-head triple projection from [rows][64] fp32 ---------------
__global__ __launch_bounds__(256) void k_proj3(
    const float* __restrict__ src, const float* Wq, const float* Wk, const float* Wv,
    float* qh, float* kh, float* vh, int nunits)
{
  __shared__ float wq[64], wk[64], wv[64];
  int t = threadIdx.x;
  if (t < 64){
    wq[t] = Wq ? Wq[t] : 0.0f;
    wk[t] = Wk[t];
    wv[t] = Wv[t];
  }
  __syncthreads();
  int u = blockIdx.x*256 + t;
  if (u >= nunits) return;
  const float* sp = src + (size_t)u*8;
  float xin[8];
#pragma unroll
  for (int d = 0; d < 8; ++d) xin[d] = sp[d];
#pragma unroll
  for (int d = 0; d < 8; ++d){
    float qa = 0.0f, ka = 0.0f, va = 0.0f;
#pragma unroll
    for (int d0 = 0; d0 < 8; ++d0){
      qa += xin[d0]*wq[d0*8 + d];
      ka += xin[d0]*wk[d0*8 + d];
      va += xin[d0]*wv[d0*8 + d];
    }
    if (qh) qh[(size_t)u*8 + d] = qa;
    kh[(size_t)u*8 + d] = ka;
    vh[(size_t)u*8 + d] = va;
  }
}

// per-row LN on the 4x4 tile (row spread across 16 lanes)
__device__ __forceinline__ void ln64(
    const float acc[4][4], float4 g, float4 b, float out[4][4])
{
#pragma unroll
  for (int i = 0; i < 4; ++i){
    float s = acc[i][0] + acc[i][1] + acc[i][2] + acc[i][3];
    float m = rowred16_sum(s) * (1.0f/64.0f);
    float d0 = acc[i][0] - m, d1 = acc[i][1] - m, d2 = acc[i][2] - m, d3 = acc[i][3] - m;
    float vv = d0*d0 + d1*d1 + d2*d2 + d3*d3;
    float var = rowred16_sum(vv) * (1.0f/64.0f);
    float rs = rsqrtf(var + 1e-5f);
    out[i][0] = d0*rs*g.x + b.x;
    out[i][1] = d1*rs*g.y + b.y;
    out[i][2] = d2*rs*g.z + b.z;
    out[i][3] = d3*rs*g.w + b.w;
  }
}

__global__ __launch_bounds__(256) void k_tail(
    const float* __restrict__ pre3, const float* __restrict__ query,
    const float* __restrict__ ds,
    const float* __restrict__ Wo, const float* __restrict__ bo,
    const float* __restrict__ g1, const float* __restrict__ be1,
    const float* __restrict__ W1, const float* __restrict__ b1,
    const float* __restrict__ W2, const float* __restrict__ b2,
    const float* __restrict__ g2, const float* __restrict__ be2,
    const float* __restrict__ Wfs, const float* __restrict__ bfs,
    float* __restrict__ outp)
{
  __shared__ float Xs[64][68];
  __shared__ float Hs[64][68];
  int tid = threadIdx.x;
  int cg = tid & 15, rg = tid >> 4;
  int r0 = rg*4, c0 = cg*4;
  int row_base = blockIdx.x * 64;            // 64 rows/block; T=128 -> n const/block
  int n = (row_base >> 7) & (Nc - 1);

  // stage pre3 tile into LDS
#pragma unroll
  for (int i = 0; i < 4; ++i){
    float4 t = *(const float4*)&pre3[(size_t)(row_base + r0 + i)*64 + c0];
    *(float4*)&Xs[r0+i][c0] = t;
  }

  float4 bo4  = *(const float4*)&bo[c0];
  float4 ds4  = *(const float4*)&ds[n*64 + c0];
  float4 g14  = *(const float4*)&g1[c0];
  float4 be14 = *(const float4*)&be1[c0];
  float4 b24  = *(const float4*)&b2[c0];
  float4 g24  = *(const float4*)&g2[c0];
  float4 be24 = *(const float4*)&be2[c0];
  float4 bfs4 = *(const float4*)&bfs[c0];
  __syncthreads();

  // ---- attn = pre3 @ Wo + bo ; v0 = attn + (query + ds) ; x = LN1(v0) ----
  float acc[4][4];
#pragma unroll
  for (int i = 0; i < 4; ++i){
    acc[i][0] = bo4.x; acc[i][1] = bo4.y; acc[i][2] = bo4.z; acc[i][3] = bo4.w;
  }
  gemm64x64(Xs, Wo, 64, r0, c0, acc);
#pragma unroll
  for (int i = 0; i < 4; ++i){
    float4 qv = *(const float4*)&query[(size_t)(row_base + r0 + i)*64 + c0];
    acc[i][0] += qv.x + ds4.x;
    acc[i][1] += qv.y + ds4.y;
    acc[i][2] += qv.z + ds4.z;
    acc[i][3] += qv.w + ds4.w;
  }
  float xt[4][4];
  ln64(acc, g14, be14, xt);
  __syncthreads();                 // all Wo-GEMM reads of Xs complete
#pragma unroll
  for (int i = 0; i < 4; ++i)
    *(float4*)&Xs[r0+i][c0] = make_float4(xt[i][0], xt[i][1], xt[i][2], xt[i][3]);
  __syncthreads();                 // Xs now holds x

  // ---- ff = relu(x @ W1 + b1) @ W2 + b2, in 4 panels of 64 hidden cols ----
  float ff[4][4];
#pragma unroll
  for (int i = 0; i < 4; ++i){
    ff[i][0] = b24.x; ff[i][1] = b24.y; ff[i][2] = b24.z; ff[i][3] = b24.w;
  }
  for (int p = 0; p < 4; ++p){
    float4 b14 = *(const float4*)&b1[p*64 + c0];
    float h[4][4];
#pragma unroll
    for (int i = 0; i < 4; ++i){
      h[i][0] = b14.x; h[i][1] = b14.y; h[i][2] = b14.z; h[i][3] = b14.w;
    }
    gemm64x64(Xs, W1 + p*64, 256, r0, c0, h);
#pragma unroll
    for (int i = 0; i < 4; ++i){
      h[i][0] = fmaxf(h[i][0], 0.0f); h[i][1] = fmaxf(h[i][1], 0.0f);
      h[i][2] = fmaxf(h[i][2], 0.0f); h[i][3] = fmaxf(h[i][3], 0.0f);
    }
    __syncthreads();               // prev panel's FF2 reads of Hs complete
#pragma unroll
    for (int i = 0; i < 4; ++i)
      *(float4*)&Hs[r0+i][c0] = make_float4(h[i][0], h[i][1], h[i][2], h[i][3]);
    __syncthreads();               // Hs holds hidden panel
    gemm64x64(Hs, W2 + (size_t)p*64*64, 64, r0, c0, ff);
  }

  // ---- u0 = ff + x ; U = LN2(u0) ----
#pragma unroll
  for (int i = 0; i < 4; ++i){
    float4 xv = *(const float4*)&Xs[r0+i][c0];
    ff[i][0] += xv.x; ff[i][1] += xv.y; ff[i][2] += xv.z; ff[i][3] += xv.w;
  }
  float U[4][4];
  ln64(ff, g24, be24, U);
  __syncthreads();                 // last FF2 reads of Hs complete
#pragma unroll
  for (int i = 0; i < 4; ++i)
    *(float4*)&Hs[r0+i][c0] = make_float4(U[i][0], U[i][1], U[i][2], U[i][3]);
  __syncthreads();                 // Hs holds U

  // ---- out = U @ Wfs + bfs ----
  float o[4][4];
#pragma unroll
  for (int i = 0; i < 4; ++i){
    o[i][0] = bfs4.x; o[i][1] = bfs4.y; o[i][2] = bfs4.z; o[i][3] = bfs4.w;
  }
  gemm64x64(Hs, Wfs, 64, r0, c0, o);
#pragma unroll
  for (int i = 0; i < 4; ++i)
    *(float4*)&outp[(size_t)(row_base + r0 + i)*64 + c0] =
        make_float4(o[i][0], o[i][1], o[i][2], o[i][3]);
}

extern "C" void kernel_launch(void* const* d_in, const int* in_sizes, int n_in,
                              void* d_out, int out_size, void* d_ws, size_t ws_size,
                              hipStream_t stream)
{
  const float* value = (const float*)d_in[0];
  const float* key   = (const float*)d_in[1];
  const float* query = (const float*)d_in[2];
  const int*  adj_sr = (const int*)d_in[3];
  const int*  adj_r  = (const int*)d_in[4];
  const float* D_S   = (const float*)d_in[5];
  const float* W_emb = (const float*)d_in[6];
  const float* b_emb = (const float*)d_in[7];
  const float* I_par = (const float*)d_in[8];
  const float* g1    = (const float*)d_in[9];
  const float* be1   = (const float*)d_in[10];
  const float* g2    = (const float*)d_in[11];
  const float* be2   = (const float*)d_in[12];
  const float* W_ff1 = (const float*)d_in[13];
  const float* b_ff1 = (const float*)d_in[14];
  const float* W_ff2 = (const float*)d_in[15];
  const float* b_ff2 = (const float*)d_in[16];
  const float* W_fs  = (const float*)d_in[17];
  const float* b_fs  = (const float*)d_in[18];
  const float* Wv_sr = (const float*)d_in[19];
  const float* Wk_sr = (const float*)d_in[20];
  const float* Wq_sr = (const float*)d_in[21];
  const float* Wo_sr = (const float*)d_in[22];
  const float* bo_sr = (const float*)d_in[23];
  const float* Wv_rr = (const float*)d_in[24];
  const float* Wk_rr = (const float*)d_in[25];
  const float* Wq_rr = (const float*)d_in[26];
  const float* Wo_rr = (const float*)d_in[27];
  const float* bo_rr = (const float*)d_in[28];
  const float* Wv_rs = (const float*)d_in[29];
  const float* Wk_rs = (const float*)d_in[30];
  const float* Wq_rs = (const float*)d_in[31];
  const float* Wo_rs = (const float*)d_in[32];
  const float* bo_rs = (const float*)d_in[33];

  float* outp  = (float*)d_out;
  float* o_out = outp;
  float* o_asr = outp + 8388608;
  float* o_arr = outp + 75497472;
  float* o_ars = outp + 83886080;
  float* o_hh  = outp + 150994944;

  // ---- workspace overlay (lifetime-checked) ----
  float* wsf = (float*)d_ws;
  float* ws_ds   = wsf;                      // 32768 floats, persistent
  float* ws_qsr  = wsf + 32768;              // 4096
  bf16*  ws_att  = (bf16*)(wsf + 36864);     // bf16 att scratch (rr stage)
  float* ws_rDsr = wsf + 36864;              // aliases ws_att head; stage-1 only,
                                             // dead before rr att use. 1M floats
  float* pool    = wsf + 36864 + 33554432;   // stage-local scratch pool
  // stage 1
  float* ws_ksr  = pool;                     // 8,388,608
  float* ws_vsr  = pool + 8388608;           // 8,388,608
  float* ws_pre1 = pool + 16777216;          // 1,048,576
  float* ws_hh1  = pool + 17825792;          // 1,048,576
  // stage 2 (ksr/vsr dead by now)
  float* ws_qrr  = pool;                     // 1,048,576
  float* ws_krr  = pool + 1048576;
  float* ws_vrr  = pool + 2097152;
  float* ws_pre2 = pool + 3145728;
  float* ws_hh2  = pool + 4194304;
  // stage 3
  float* ws_krs  = pool + 5242880;
  float* ws_vrs  = pool + 6291456;
  float* ws_pre3 = pool + 7340032;           // 8,388,608
  float* ws_rDrs = pool + 15728640;          // 131,072  [B][K][T][H]

  // ---- stage 1: sr attention (denominator+asr writer first, then PV) ----
  k_prep<<<576, 64, 0, stream>>>(D_S, W_emb, b_emb, I_par, Wq_sr, ws_ds, ws_qsr);
  k_proj_sr<<<4096, 256, 0, stream>>>(key, value, ws_ds, Wk_sr, Wv_sr, ws_ksr, ws_vsr);
  k_asr_write<<<512, 256, 0, stream>>>(ws_ksr, ws_qsr, adj_sr, o_asr, ws_rDsr);
  k_attn_sr<<<2048, 256, 0, stream>>>(ws_ksr, ws_vsr, ws_qsr, adj_sr,
                                      ws_rDsr, ws_pre1);
  k_wo<<<256, 256, 0, stream>>>(ws_pre1, Wo_sr, bo_sr, ws_hh1, (float*)nullptr);

  // ---- stage 2: rr attention ----
  k_proj3<<<512, 256, 0, stream>>>(ws_hh1, Wq_rr, Wk_rr, Wv_rr,
                                   ws_qrr, ws_krr, ws_vrr, 131072);
  k_attn_rr<<<2048, 256, 0, stream>>>(ws_qrr, ws_krr, ws_vrr, adj_r, ws_att, ws_pre2);
  k_transpose<<<2048, 256, 0, stream>>>((const unsigned short*)ws_att, o_arr, 64, 64);
  k_wo<<<256, 256, 0, stream>>>(ws_pre2, Wo_rr, bo_rr, ws_hh2, o_hh);

  // ---- stage 3: rs attention (PV+denominators, then coalesced ars writer) ----
  k_proj3<<<512, 256, 0, stream>>>(ws_hh2, (const float*)nullptr, Wk_rs, Wv_rs,
                                   (float*)nullptr, ws_krs, ws_vrs, 131072);
  k_attn_rs<<<2048, 512, 0, stream>>>(query, ws_ds, Wq_rs, ws_krs, ws_vrs,
                                      ws_rDrs, ws_pre3);
  k_ars_write<<<256, 512, 0, stream>>>(query, ws_ds, Wq_rs, ws_krs,
                                       ws_rDrs, o_ars);

  // ---- tail: Wo_rs + LN + FF + LN + W_fs (fused, LDS-tiled fp32 GEMM) ----
  k_tail<<<2048, 256, 0, stream>>>(ws_pre3, query, ws_ds, Wo_rs, bo_rs,
                                   g1, be1, W_ff1, b_ff1, W_ff2, b_ff2,
                                   g2, be2, W_fs, b_fs, o_out);
}